// Round 3
// baseline (3109.757 us; speedup 1.0000x reference)
//
#include <hip/hip_runtime.h>
#include <math.h>

// Problem constants (reference: B,T,V,E,H = 32,512,32000,300,256)
#define BB 32
#define TT_LEN 512
#define EE 300
#define HH 256
#define G4 1024          // 4*H
#define CMAX 155         // int(round(0.3*512))+1
#define TRANS_T 10.0f    // TRANSITION/TEMP
#define NEGF -1.0e9f
#define INV_TEMP 100.0f  // 1/TEMP
#define AST_STRIDE 159   // slot-2 accesses predicated l<27 (max off 154)

typedef _Float16 half2v __attribute__((ext_vector_type(2)));
typedef _Float16 half8 __attribute__((ext_vector_type(8)));
typedef float f32x4 __attribute__((ext_vector_type(4)));

__device__ __forceinline__ float la(float x, float y) {
  float m = fmaxf(x, y);
  float d = fminf(x, y) - m;
  return m + __logf(1.0f + __expf(d));
}

__device__ __forceinline__ float sigm(float x) {
  return 1.0f / (1.0f + __expf(-x));
}

__device__ __forceinline__ float tanh_f(float x) {
  // fast tanh via exp2-backed __expf; clamp prevents inf/inf on pathological c
  x = fminf(fmaxf(x, -15.f), 15.f);
  float e = __expf(2.f * x);
  return (e - 1.f) * __frcp_rn(e + 1.f);
}

__device__ __forceinline__ unsigned int packh(float a, float b) {
  half2v hp;
  hp.x = (_Float16)a;
  hp.y = (_Float16)b;
  return __builtin_bit_cast(unsigned int, hp);
}

__device__ __forceinline__ float2 h2f(unsigned int d) {
  half2v h = __builtin_bit_cast(half2v, d);
  return make_float2((float)h.x, (float)h.y);
}

__device__ __forceinline__ unsigned short f16b(float x) {
  _Float16 h = (_Float16)x;
  return __builtin_bit_cast(unsigned short, h);
}

// column mapping: gate-column n (0..1023) -> source column g*HH+u with
// g = gate type, u = unit. Chosen so that in the LSTM, wave w / ntile nt /
// col c gets gate g = nt&3 of unit u = w*32 + ((nt>>2)&1)*16 + c.
// This mapping must be used consistently by wi_frag, b_p, wh frags.
__device__ __forceinline__ int nmap_col(int n) {
  int g = (n >> 4) & 3;
  int u = (n >> 7) * 32 + ((n >> 6) & 1) * 16 + (n & 15);
  return g * HH + u;
}

// ---------------- K0: weight prep ------------------------------------------
// wi_frag: B-fragments for xg_mfma (remapped columns)
// whr: Wh B-fragments kt=0..5  [dir][kt][nb][lane] uint4
// whl: Wh B-fragments kt=6..7  [dir][kt-6][nb][lane] uint4
__global__ void prep_weights(const float* wi_f, const float* wi_b,
                             const float* wh_f, const float* wh_b,
                             const float* b_f, const float* b_b,
                             unsigned int* wi_frag, float* b_p,
                             uint4* whr, uint4* whl) {
  int idx = blockIdx.x * blockDim.x + threadIdx.x;
  int stride = gridDim.x * blockDim.x;
  for (int i = idx; i < 2 * 64 * 10 * 64 * 4; i += stride) {
    int u4 = i >> 2, d = i & 3;
    int lane = u4 & 63;
    int kk = (u4 >> 6) % 10;
    int nb = (u4 / 640) & 63;
    int dir = u4 / (640 * 64);
    int l15 = lane & 15, quad = lane >> 4;
    int col = nmap_col(nb * 16 + l15);
    int k0 = kk * 32 + quad * 8 + 2 * d;
    const float* src = dir ? wi_b : wi_f;
    float v0 = (k0 < EE) ? src[(size_t)k0 * G4 + col] : 0.0f;
    float v1 = (k0 + 1 < EE) ? src[(size_t)(k0 + 1) * G4 + col] : 0.0f;
    wi_frag[i] = packh(v0, v1);
  }
  for (int i = idx; i < 2 * 8 * 64 * 64; i += stride) {
    int lane = i & 63;
    int nb = (i >> 6) & 63;
    int kt = (i >> 12) & 7;
    int dir = i >> 15;
    int c = lane & 15, q = lane >> 4;
    int col = nmap_col(nb * 16 + c);
    int k0 = kt * 32 + q * 8;
    const float* src = dir ? wh_b : wh_f;
    uint4 o;
    o.x = packh(src[(size_t)(k0 + 0) * G4 + col], src[(size_t)(k0 + 1) * G4 + col]);
    o.y = packh(src[(size_t)(k0 + 2) * G4 + col], src[(size_t)(k0 + 3) * G4 + col]);
    o.z = packh(src[(size_t)(k0 + 4) * G4 + col], src[(size_t)(k0 + 5) * G4 + col]);
    o.w = packh(src[(size_t)(k0 + 6) * G4 + col], src[(size_t)(k0 + 7) * G4 + col]);
    if (kt < 6)
      whr[((size_t)(dir * 6 + kt) * 64 + nb) * 64 + lane] = o;
    else
      whl[((size_t)(dir * 2 + kt - 6) * 64 + nb) * 64 + lane] = o;
  }
  for (int i = idx; i < 2 * G4; i += stride) {
    int dir = i / G4;
    int j = i % G4;
    const float* src = dir ? b_b : b_f;
    b_p[i] = src[nmap_col(j)];
  }
}

// ---------------- K_emb: gather -> A-fragment layout -----------------------
// m-tile mblk = bg*512 + t holds 16 BATCH rows (bg*16..bg*16+15) at time t.
__global__ void gather_emb(const int* x, const float* embed, uint4* emb_frag) {
  int mblk = blockIdx.x;
  int t = threadIdx.x;
  int bg = mblk >> 9, tloc = mblk & 511;
  __shared__ int xs[16];
  if (t < 16) xs[t] = x[(bg * 16 + t) * TT_LEN + tloc];
  __syncthreads();
  for (int slot = t; slot < 640; slot += 256) {
    int kk = slot >> 6;
    int lane = slot & 63;
    int l15 = lane & 15, quad = lane >> 4;
    int row = xs[l15];
    int kbase = kk * 32 + quad * 8;
    const float* src = embed + (size_t)row * EE;
    float v[8];
#pragma unroll
    for (int e = 0; e < 8; ++e) v[e] = (kbase + e < EE) ? src[kbase + e] : 0.0f;
    uint4 o;
    o.x = packh(v[0], v[1]);
    o.y = packh(v[2], v[3]);
    o.z = packh(v[4], v[5]);
    o.w = packh(v[6], v[7]);
    emb_frag[(size_t)(mblk * 10 + kk) * 64 + lane] = o;
  }
}

// ---------------- K1: xg = emb @ wi^T + b, stored as f16 D-fragments -------
// xg_frag[((dir*1024 + mblk)*32 + nb2)*64 + lane] = uint4:
//   .x/.y = rows 0-1 / 2-3 of col-tile 2*nb2, .z/.w = of col-tile 2*nb2+1
__global__ __launch_bounds__(256) void xg_mfma(
    const uint4* __restrict__ emb_frag, const uint4* __restrict__ wi_frag,
    const float* __restrict__ b_p, uint4* __restrict__ xg_frag) {
  int dir = blockIdx.z;
  int w = threadIdx.x >> 6;
  int lane = threadIdx.x & 63;
  int l15 = lane & 15;
  int mblk = blockIdx.y * 4 + w;

  const uint4* abase = emb_frag + (size_t)mblk * 10 * 64 + lane;
  f32x4 acc[4];
#pragma unroll
  for (int nt = 0; nt < 4; ++nt) acc[nt] = (f32x4){0.f, 0.f, 0.f, 0.f};

#pragma unroll
  for (int kk = 0; kk < 10; ++kk) {
    half8 a = __builtin_bit_cast(half8, abase[kk * 64]);
#pragma unroll
    for (int nt = 0; nt < 4; ++nt) {
      int nb = blockIdx.x * 4 + nt;
      half8 b = __builtin_bit_cast(
          half8, wi_frag[((size_t)(dir * 64 + nb) * 10 + kk) * 64 + lane]);
      acc[nt] = __builtin_amdgcn_mfma_f32_16x16x32_f16(a, b, acc[nt], 0, 0, 0);
    }
  }
#pragma unroll
  for (int ntp = 0; ntp < 2; ++ntp) {
    float bA = b_p[dir * G4 + (blockIdx.x * 4 + 2 * ntp) * 16 + l15];
    float bB = b_p[dir * G4 + (blockIdx.x * 4 + 2 * ntp + 1) * 16 + l15];
    f32x4 aA = acc[2 * ntp], aB = acc[2 * ntp + 1];
    uint4 o;
    o.x = packh(aA[0] + bA, aA[1] + bA);
    o.y = packh(aA[2] + bA, aA[3] + bA);
    o.z = packh(aB[0] + bB, aB[1] + bB);
    o.w = packh(aB[2] + bB, aB[3] + bB);
    xg_frag[((size_t)(dir * 1024 + mblk) * 32 + blockIdx.x * 2 + ntp) * 64 + lane] = o;
  }
}

// ---------------- K2: batched-MFMA LSTM ------------------------------------
// 4 blocks = (dir, bgroup). Each block: 16 batch recurrences, M=16 MFMA.
// Weights: 46 B-frags/thread in regs (184 VGPR) + 152KB LDS (kt 6,7 full +
// kt5 nt{6,7}). h handoff via 8KB XOR-swizzled LDS ([m][u^((m&7)<<3)] f16).
// __launch_bounds__(512) (NOT (512,2)): 8 waves / 4 SIMDs = 2 waves/SIMD
// -> 256-VGPR cap. Round-2's (512,2) capped at 128 and spilled ~130 regs.
// xc,xd loads moved after the barrier: -8 regs of in-loop pressure; their
// latency hides under ph0's sigmoid/tanh chain.
__global__ __launch_bounds__(512) void lstm_mfma(
    const uint4* __restrict__ xg_frag, const uint4* __restrict__ whr,
    const uint4* __restrict__ whl, unsigned short* __restrict__ h16g) {
  int dir = blockIdx.x >> 1, bg = blockIdx.x & 1;
  int t = threadIdx.x;
  int lane = t & 63, w = t >> 6;
  int c = lane & 15, q = lane >> 4;

  __shared__ uint4 wlds[2 * 64 * 64];        // 128 KB: kt 6,7
  __shared__ uint4 wlds5[16 * 64];           // 16 KB: kt 5, nt 6,7
  __shared__ unsigned short hsw[16 * 256];   // 8 KB swizzled h

  for (int i = t; i < 8192; i += 512) wlds[i] = whl[(size_t)dir * 8192 + i];
  for (int i = t; i < 1024; i += 512) {
    int widx = i >> 7, sub = (i >> 6) & 1, l2 = i & 63;
    wlds5[i] = whr[((size_t)(dir * 6 + 5) * 64 + widx * 8 + 6 + sub) * 64 + l2];
  }
  for (int i = t; i < 2048; i += 512) ((unsigned int*)hsw)[i] = 0;

  uint4 wreg[46];
#pragma unroll
  for (int kt = 0; kt < 5; ++kt)
#pragma unroll
    for (int nt = 0; nt < 8; ++nt)
      wreg[kt * 8 + nt] =
          whr[((size_t)(dir * 6 + kt) * 64 + w * 8 + nt) * 64 + lane];
#pragma unroll
  for (int nt = 0; nt < 6; ++nt)
    wreg[40 + nt] = whr[((size_t)(dir * 6 + 5) * 64 + w * 8 + nt) * 64 + lane];

  float cst[8];
#pragma unroll
  for (int i = 0; i < 8; ++i) cst[i] = 0.f;

  const uint4* xgb =
      xg_frag + ((size_t)(dir * 1024 + bg * 512) * 32 + w * 4) * 64 + lane;
  unsigned short* hgb = h16g + (size_t)dir * 4194304 + bg * 16 + 4 * q;
  const int xk = (c & 7) << 3;

  __syncthreads();

#pragma unroll 1
  for (int s = 0; s < TT_LEN; ++s) {
    int tt = dir ? (TT_LEN - 1 - s) : s;
    const uint4* xp = xgb + (size_t)tt * 2048;
    uint4 xa = xp[0];
    uint4 xb = xp[64];
    f32x4 D[8];
#pragma unroll
    for (int nt = 0; nt < 8; ++nt) D[nt] = (f32x4){0.f, 0.f, 0.f, 0.f};
#pragma unroll
    for (int kt = 0; kt < 8; ++kt) {
      half8 A = *(const half8*)(hsw + (c * 256 + ((kt * 32 + q * 8) ^ xk)));
#pragma unroll
      for (int nt = 0; nt < 8; ++nt) {
        uint4 bw;
        if (kt < 5)
          bw = wreg[kt * 8 + nt];
        else if (kt == 5)
          bw = (nt < 6) ? wreg[40 + nt] : wlds5[(w * 2 + nt - 6) * 64 + lane];
        else
          bw = wlds[((kt - 6) * 64 + w * 8 + nt) * 64 + lane];
        D[nt] = __builtin_amdgcn_mfma_f32_16x16x32_f16(
            A, __builtin_bit_cast(half8, bw), D[nt], 0, 0, 0);
      }
    }
    __syncthreads();  // all A-reads done -> hsw writable
    uint4 xc = xp[128];
    uint4 xd = xp[192];
#pragma unroll
    for (int ph = 0; ph < 2; ++ph) {
      uint4 va = ph ? xc : xa;
      uint4 vb = ph ? xd : xb;
      float2 p0 = h2f(va.x), p1 = h2f(va.y), p2 = h2f(va.z), p3 = h2f(va.w);
      float2 p4 = h2f(vb.x), p5 = h2f(vb.y), p6 = h2f(vb.z), p7 = h2f(vb.w);
      float xi[4] = {p0.x, p0.y, p1.x, p1.y};
      float xf[4] = {p2.x, p2.y, p3.x, p3.y};
      float xgv[4] = {p4.x, p4.y, p5.x, p5.y};
      float xo[4] = {p6.x, p6.y, p7.x, p7.y};
      int u = w * 32 + ph * 16 + c;
      float hv[4];
#pragma unroll
      for (int r = 0; r < 4; ++r) {
        float I = sigm(D[ph * 4 + 0][r] + xi[r]);
        float F = sigm(D[ph * 4 + 1][r] + xf[r]);
        float G = tanh_f(D[ph * 4 + 2][r] + xgv[r]);
        float O = sigm(D[ph * 4 + 3][r] + xo[r]);
        float cn = F * cst[ph * 4 + r] + I * G;
        cst[ph * 4 + r] = cn;
        float h = O * tanh_f(cn);
        hv[r] = h;
        int m = 4 * q + r;
        hsw[m * 256 + (u ^ ((m & 7) << 3))] = f16b(h);
      }
      uint2 pk;
      pk.x = packh(hv[0], hv[1]);
      pk.y = packh(hv[2], hv[3]);
      *(uint2*)(hgb + ((size_t)tt * 8192 + u * 32)) = pk;  // fire-and-forget
    }
    __syncthreads();  // h ready for next step
  }
}

// ---------------- K3: scores = h . w_out (off the critical path) ----------
__global__ __launch_bounds__(64) void hscore(
    const unsigned short* __restrict__ h16g, const float* __restrict__ w_out,
    float* __restrict__ scores_part) {
  int dt = blockIdx.x;          // 0..1023 = dir*512 + t
  int dir = dt >> 9, tpos = dt & 511;
  int l = threadIdx.x;
  int b = l & 31, uh = l >> 5;
  const unsigned short* base =
      h16g + (((size_t)dir * 512 + tpos) * 256 + uh * 128) * 32 + b;
  const float* wo = w_out + dir * HH + uh * 128;
  float s = 0.f;
#pragma unroll 8
  for (int u = 0; u < 128; ++u) {
    _Float16 hv = __builtin_bit_cast(_Float16, base[(size_t)u * 32]);
    s += (float)hv * wo[u];
  }
  s += __shfl_down(s, 32, 64);
  if (uh == 0) scores_part[((size_t)dir * BB + b) * TT_LEN + tpos] = s;
}

// ---------------- K4: CRF fwd+bwd in PARALLEL WAVES ------------------------
__global__ __launch_bounds__(128) void dp3(const float* __restrict__ scores_part,
                                           const float* __restrict__ b_out,
                                           float* __restrict__ ast_g,
                                           float* __restrict__ bst_g,
                                           float* __restrict__ lzv) {
  int b = blockIdx.x;
  int l = threadIdx.x & 63;
  int w = threadIdx.x >> 6;
  const float* spf = scores_part + (size_t)b * TT_LEN;
  const float* spb = scores_part + (size_t)(BB + b) * TT_LEN;
  float bo = b_out[0];

  float ur[8];
#pragma unroll
  for (int i = 0; i < 8; ++i)
    ur[i] = (spf[i * 64 + l] + spb[i * 64 + l] + bo) * INV_TEMP;

  if (w == 0) {
    // ---------------- forward ----------------
    float* ast = ast_g + (size_t)b * TT_LEN * AST_STRIDE;
    int lm1 = (l + 63) & 63;
    float a0[3], a1[3];
    float u00 = __shfl(ur[0], 0, 64);
    a0[0] = (l == 1) ? (u00 + TRANS_T) : NEGF;
    a0[1] = NEGF;
    a0[2] = NEGF;
    a1[0] = (l == 0) ? 0.0f : NEGF;
    a1[1] = NEGF;
    a1[2] = NEGF;
    ast[l] = a0[0];
    ast[64 + l] = a0[1];
    if (l < 27) ast[128 + l] = a0[2];

#pragma unroll
    for (int ch = 0; ch < 8; ++ch) {
      float uc = ur[ch];
#pragma unroll 4
      for (int tt = (ch == 0 ? 1 : 0); tt < 64; ++tt) {
        int t = ch * 64 + tt;
        float u0t = __shfl(uc, tt, 64);
        float w0a = __shfl(a0[0], lm1, 64);
        float w1a = __shfl(a0[1], lm1, 64);
        float w2a = __shfl(a0[2], lm1, 64);
        float w0b = __shfl(a1[0], lm1, 64);
        float w1b = __shfl(a1[1], lm1, 64);
        float w2b = __shfl(a1[2], lm1, 64);
        float p0a = (l == 0) ? NEGF : w0a;
        float p1a = (l == 0) ? w0a : w1a;
        float p2a = (l == 0) ? w1a : w2a;
        float p0b = (l == 0) ? NEGF : w0b;
        float p1b = (l == 0) ? w0b : w1b;
        float p2b = (l == 0) ? w1b : w2b;
        float n00 = u0t + la(p0a + TRANS_T, p0b);
        float n01 = u0t + la(p1a + TRANS_T, p1b);
        float n02 = u0t + la(p2a + TRANS_T, p2b);
        float n10 = la(a0[0], a1[0]);
        float n11 = la(a0[1], a1[1]);
        float n12 = la(a0[2], a1[2]);
        a0[0] = n00;
        a0[1] = n01;
        a0[2] = (l < 27) ? n02 : NEGF;
        a1[0] = n10;
        a1[1] = n11;
        a1[2] = (l < 27) ? n12 : NEGF;
        float* astr = ast + (size_t)t * AST_STRIDE;
        astr[l] = a0[0];
        astr[64 + l] = a0[1];
        if (l < 27) astr[128 + l] = a0[2];
      }
    }
    // logZ
    float f00 = a0[0] + TRANS_T, f01 = a0[1] + TRANS_T, f02 = a0[2] + TRANS_T;
    float m = fmaxf(fmaxf(fmaxf(f00, f01), fmaxf(f02, a1[0])),
                    fmaxf(a1[1], a1[2]));
#pragma unroll
    for (int off = 32; off > 0; off >>= 1) m = fmaxf(m, __shfl_xor(m, off, 64));
    float es = __expf(f00 - m) + __expf(f01 - m) + __expf(f02 - m) +
               __expf(a1[0] - m) + __expf(a1[1] - m) + __expf(a1[2] - m);
#pragma unroll
    for (int off = 32; off > 0; off >>= 1) es += __shfl_xor(es, off, 64);
    if (l == 0) lzv[b] = m + __logf(es);
  } else {
    // ---------------- backward (independent of alpha) ----------------
    float* bst = bst_g + (size_t)b * TT_LEN * AST_STRIDE;
    int lp1 = (l + 1) & 63;
    float b0[3], b1[3];
    b0[0] = TRANS_T;
    b0[1] = TRANS_T;
    b0[2] = (l < 27) ? TRANS_T : NEGF;
    b1[0] = 0.0f;
    b1[1] = 0.0f;
    b1[2] = (l < 27) ? 0.0f : NEGF;
    {
      float* br = bst + (size_t)(TT_LEN - 1) * AST_STRIDE;
      br[l] = b0[0];
      br[64 + l] = b0[1];
      if (l < 27) br[128 + l] = b0[2];
    }
#pragma unroll
    for (int ch = 7; ch >= 0; --ch) {
      float uc = ur[ch];
#pragma unroll 4
      for (int tt = 63; tt >= (ch == 0 ? 1 : 0); --tt) {
        int t = ch * 64 + tt;
        float u0t = __shfl(uc, tt, 64);
        float w0 = __shfl(b0[0], lp1, 64);
        float w1 = __shfl(b0[1], lp1, 64);
        float w2 = __shfl(b0[2], lp1, 64);
        float x2 = (l == 63) ? NEGF : w2;
        float x1 = (l == 63) ? w2 : w1;
        float x0 = (l == 63) ? w1 : w0;
        float nb00 = la(u0t + TRANS_T + x0, b1[0]);
        float nb01 = la(u0t + TRANS_T + x1, b1[1]);
        float nb02 = la(u0t + TRANS_T + x2, b1[2]);
        float nb10 = la(u0t + x0, b1[0]);
        float nb11 = la(u0t + x1, b1[1]);
        float nb12 = la(u0t + x2, b1[2]);
        b0[0] = nb00;
        b0[1] = nb01;
        b0[2] = (l < 27) ? nb02 : NEGF;
        b1[0] = nb10;
        b1[1] = nb11;
        b1[2] = (l < 27) ? nb12 : NEGF;
        float* br = bst + (size_t)(t - 1) * AST_STRIDE;
        br[l] = b0[0];
        br[64 + l] = b0[1];
        if (l < 27) br[128 + l] = b0[2];
      }
    }
  }
}

// ---------------- K5: marginals, fully parallel ----------------------------
__global__ __launch_bounds__(256) void marg(const float* __restrict__ ast_g,
                                            const float* __restrict__ bst_g,
                                            const float* __restrict__ lzv,
                                            float* __restrict__ out) {
  int row = blockIdx.x * 4 + (threadIdx.x >> 6);
  int l = threadIdx.x & 63;
  int b = row >> 9;
  const float* ar = ast_g + (size_t)row * AST_STRIDE;
  const float* br = bst_g + (size_t)row * AST_STRIDE;
  float lz = lzv[b];
  float s = __expf(ar[l] + br[l] - lz) + __expf(ar[64 + l] + br[64 + l] - lz) +
            ((l < 27) ? __expf(ar[128 + l] + br[128 + l] - lz) : 0.0f);
#pragma unroll
  for (int off = 32; off > 0; off >>= 1) s += __shfl_xor(s, off, 64);
  if (l == 0) out[row] = s;
}

// ---------------------------------------------------------------------------
extern "C" void kernel_launch(void* const* d_in, const int* in_sizes, int n_in,
                              void* d_out, int out_size, void* d_ws, size_t ws_size,
                              hipStream_t stream) {
  const int* x = (const int*)d_in[0];
  const float* embed = (const float*)d_in[3];
  const float* wi_f = (const float*)d_in[4];
  const float* wh_f = (const float*)d_in[5];
  const float* bf = (const float*)d_in[6];
  const float* wi_b = (const float*)d_in[7];
  const float* wh_b = (const float*)d_in[8];
  const float* bbias = (const float*)d_in[9];
  const float* w_out = (const float*)d_in[10];
  const float* b_out = (const float*)d_in[11];

  float* ws = (float*)d_ws;
  float* b_p = ws;                                            // 2048 f32
  unsigned int* wi_frag = (unsigned int*)(b_p + 2 * G4);      // 327680 dw
  uint4* whr = (uint4*)(wi_frag + 2 * 64 * 10 * 64 * 4);      // 49152 uint4
  uint4* whl = whr + 49152;                                   // 16384 uint4
  uint4* emb_frag = whl + 16384;                              // 655360 uint4
  uint4* xg_frag = emb_frag + 655360;                         // 4194304 uint4
  unsigned short* h16g = (unsigned short*)(xg_frag + 4194304);  // 8388608 us
  float* scores_part = (float*)(h16g + 8388608);              // 32768 f32
  float* lzv = scores_part + 2 * BB * TT_LEN;                 // 32 (+pad)
  float* ast_g = lzv + 64;                                    // 32*512*159 f32
  // bst aliases emb_frag (dead after xg_mfma): 10.42 MB fits in 10.49 MB
  float* bst_g = (float*)emb_frag;
  float* outp = (float*)d_out;

  prep_weights<<<256, 256, 0, stream>>>(wi_f, wi_b, wh_f, wh_b, bf, bbias,
                                        wi_frag, b_p, whr, whl);
  gather_emb<<<(BB * TT_LEN) / 16, 256, 0, stream>>>(x, embed, emb_frag);
  dim3 g1(16, 256, 2);
  xg_mfma<<<g1, 256, 0, stream>>>(emb_frag, (const uint4*)wi_frag, b_p, xg_frag);
  lstm_mfma<<<4, 512, 0, stream>>>(xg_frag, whr, whl, h16g);
  hscore<<<2 * TT_LEN, 64, 0, stream>>>(h16g, w_out, scores_part);
  dp3<<<BB, 128, 0, stream>>>(scores_part, b_out, ast_g, bst_g, lzv);
  marg<<<(BB * TT_LEN) / 4, 256, 0, stream>>>(ast_g, bst_g, lzv, outp);
}

// Round 4
// 3107.530 us; speedup vs baseline: 1.0007x; 1.0007x over previous
//
#include <hip/hip_runtime.h>
#include <math.h>

// Problem constants (reference: B,T,V,E,H = 32,512,32000,300,256)
#define BB 32
#define TT_LEN 512
#define EE 300
#define HH 256
#define G4 1024          // 4*H
#define CMAX 155         // int(round(0.3*512))+1
#define TRANS_T 10.0f    // TRANSITION/TEMP
#define NEGF -1.0e9f
#define INV_TEMP 100.0f  // 1/TEMP
#define AST_STRIDE 159   // slot-2 accesses predicated l<27 (max off 154)

typedef _Float16 half2v __attribute__((ext_vector_type(2)));
typedef _Float16 half8 __attribute__((ext_vector_type(8)));
typedef float f32x4 __attribute__((ext_vector_type(4)));

__device__ __forceinline__ float la(float x, float y) {
  float m = fmaxf(x, y);
  float d = fminf(x, y) - m;
  return m + __logf(1.0f + __expf(d));
}

__device__ __forceinline__ float sigm(float x) {
  return 1.0f / (1.0f + __expf(-x));
}

__device__ __forceinline__ float tanh_f(float x) {
  // fast tanh via exp2-backed __expf; clamp prevents inf/inf on pathological c
  x = fminf(fmaxf(x, -15.f), 15.f);
  float e = __expf(2.f * x);
  return (e - 1.f) * __frcp_rn(e + 1.f);
}

__device__ __forceinline__ unsigned int packh(float a, float b) {
  half2v hp;
  hp.x = (_Float16)a;
  hp.y = (_Float16)b;
  return __builtin_bit_cast(unsigned int, hp);
}

__device__ __forceinline__ float2 h2f(unsigned int d) {
  half2v h = __builtin_bit_cast(half2v, d);
  return make_float2((float)h.x, (float)h.y);
}

__device__ __forceinline__ unsigned short f16b(float x) {
  _Float16 h = (_Float16)x;
  return __builtin_bit_cast(unsigned short, h);
}

// column mapping: gate-column n (0..1023) -> source column g*HH+u with
// g = gate type, u = unit. Chosen so that in the LSTM, wave w / ntile nt /
// col c gets gate g = nt&3 of unit u = w*32 + ((nt>>2)&1)*16 + c.
// This mapping must be used consistently by wi_frag, b_p, wh frags.
__device__ __forceinline__ int nmap_col(int n) {
  int g = (n >> 4) & 3;
  int u = (n >> 7) * 32 + ((n >> 6) & 1) * 16 + (n & 15);
  return g * HH + u;
}

// ---------------- K0: weight prep ------------------------------------------
// wi_frag: B-fragments for xg_mfma (remapped columns)
// whr: Wh B-fragments kt=0..5  [dir][kt][nb][lane] uint4
// whl: Wh B-fragments kt=6..7  [dir][kt-6][nb][lane] uint4
__global__ void prep_weights(const float* wi_f, const float* wi_b,
                             const float* wh_f, const float* wh_b,
                             const float* b_f, const float* b_b,
                             unsigned int* wi_frag, float* b_p,
                             uint4* whr, uint4* whl) {
  int idx = blockIdx.x * blockDim.x + threadIdx.x;
  int stride = gridDim.x * blockDim.x;
  for (int i = idx; i < 2 * 64 * 10 * 64 * 4; i += stride) {
    int u4 = i >> 2, d = i & 3;
    int lane = u4 & 63;
    int kk = (u4 >> 6) % 10;
    int nb = (u4 / 640) & 63;
    int dir = u4 / (640 * 64);
    int l15 = lane & 15, quad = lane >> 4;
    int col = nmap_col(nb * 16 + l15);
    int k0 = kk * 32 + quad * 8 + 2 * d;
    const float* src = dir ? wi_b : wi_f;
    float v0 = (k0 < EE) ? src[(size_t)k0 * G4 + col] : 0.0f;
    float v1 = (k0 + 1 < EE) ? src[(size_t)(k0 + 1) * G4 + col] : 0.0f;
    wi_frag[i] = packh(v0, v1);
  }
  for (int i = idx; i < 2 * 8 * 64 * 64; i += stride) {
    int lane = i & 63;
    int nb = (i >> 6) & 63;
    int kt = (i >> 12) & 7;
    int dir = i >> 15;
    int c = lane & 15, q = lane >> 4;
    int col = nmap_col(nb * 16 + c);
    int k0 = kt * 32 + q * 8;
    const float* src = dir ? wh_b : wh_f;
    uint4 o;
    o.x = packh(src[(size_t)(k0 + 0) * G4 + col], src[(size_t)(k0 + 1) * G4 + col]);
    o.y = packh(src[(size_t)(k0 + 2) * G4 + col], src[(size_t)(k0 + 3) * G4 + col]);
    o.z = packh(src[(size_t)(k0 + 4) * G4 + col], src[(size_t)(k0 + 5) * G4 + col]);
    o.w = packh(src[(size_t)(k0 + 6) * G4 + col], src[(size_t)(k0 + 7) * G4 + col]);
    if (kt < 6)
      whr[((size_t)(dir * 6 + kt) * 64 + nb) * 64 + lane] = o;
    else
      whl[((size_t)(dir * 2 + kt - 6) * 64 + nb) * 64 + lane] = o;
  }
  for (int i = idx; i < 2 * G4; i += stride) {
    int dir = i / G4;
    int j = i % G4;
    const float* src = dir ? b_b : b_f;
    b_p[i] = src[nmap_col(j)];
  }
}

// ---------------- K_emb: gather -> A-fragment layout -----------------------
// m-tile mblk = bg*512 + t holds 16 BATCH rows (bg*16..bg*16+15) at time t.
__global__ void gather_emb(const int* x, const float* embed, uint4* emb_frag) {
  int mblk = blockIdx.x;
  int t = threadIdx.x;
  int bg = mblk >> 9, tloc = mblk & 511;
  __shared__ int xs[16];
  if (t < 16) xs[t] = x[(bg * 16 + t) * TT_LEN + tloc];
  __syncthreads();
  for (int slot = t; slot < 640; slot += 256) {
    int kk = slot >> 6;
    int lane = slot & 63;
    int l15 = lane & 15, quad = lane >> 4;
    int row = xs[l15];
    int kbase = kk * 32 + quad * 8;
    const float* src = embed + (size_t)row * EE;
    float v[8];
#pragma unroll
    for (int e = 0; e < 8; ++e) v[e] = (kbase + e < EE) ? src[kbase + e] : 0.0f;
    uint4 o;
    o.x = packh(v[0], v[1]);
    o.y = packh(v[2], v[3]);
    o.z = packh(v[4], v[5]);
    o.w = packh(v[6], v[7]);
    emb_frag[(size_t)(mblk * 10 + kk) * 64 + lane] = o;
  }
}

// ---------------- K1: xg = emb @ wi^T + b, stored as f16 D-fragments -------
// xg_frag[((dir*1024 + mblk)*32 + nb2)*64 + lane] = uint4:
//   .x/.y = rows 0-1 / 2-3 of col-tile 2*nb2, .z/.w = of col-tile 2*nb2+1
__global__ __launch_bounds__(256) void xg_mfma(
    const uint4* __restrict__ emb_frag, const uint4* __restrict__ wi_frag,
    const float* __restrict__ b_p, uint4* __restrict__ xg_frag) {
  int dir = blockIdx.z;
  int w = threadIdx.x >> 6;
  int lane = threadIdx.x & 63;
  int l15 = lane & 15;
  int mblk = blockIdx.y * 4 + w;

  const uint4* abase = emb_frag + (size_t)mblk * 10 * 64 + lane;
  f32x4 acc[4];
#pragma unroll
  for (int nt = 0; nt < 4; ++nt) acc[nt] = (f32x4){0.f, 0.f, 0.f, 0.f};

#pragma unroll
  for (int kk = 0; kk < 10; ++kk) {
    half8 a = __builtin_bit_cast(half8, abase[kk * 64]);
#pragma unroll
    for (int nt = 0; nt < 4; ++nt) {
      int nb = blockIdx.x * 4 + nt;
      half8 b = __builtin_bit_cast(
          half8, wi_frag[((size_t)(dir * 64 + nb) * 10 + kk) * 64 + lane]);
      acc[nt] = __builtin_amdgcn_mfma_f32_16x16x32_f16(a, b, acc[nt], 0, 0, 0);
    }
  }
#pragma unroll
  for (int ntp = 0; ntp < 2; ++ntp) {
    float bA = b_p[dir * G4 + (blockIdx.x * 4 + 2 * ntp) * 16 + l15];
    float bB = b_p[dir * G4 + (blockIdx.x * 4 + 2 * ntp + 1) * 16 + l15];
    f32x4 aA = acc[2 * ntp], aB = acc[2 * ntp + 1];
    uint4 o;
    o.x = packh(aA[0] + bA, aA[1] + bA);
    o.y = packh(aA[2] + bA, aA[3] + bA);
    o.z = packh(aB[0] + bB, aB[1] + bB);
    o.w = packh(aB[2] + bB, aB[3] + bB);
    xg_frag[((size_t)(dir * 1024 + mblk) * 32 + blockIdx.x * 2 + ntp) * 64 + lane] = o;
  }
}

// ---------------- K2: batched-MFMA LSTM ------------------------------------
// 4 blocks = (dir, bgroup). Each block: 16 batch recurrences, M=16 MFMA.
// Weights: 46 B-frags/thread in regs (184 VGPR) + 152KB LDS (kt 6,7 full +
// kt5 nt{6,7}). h handoff via 8KB XOR-swizzled LDS ([m][u^((m&7)<<3)] f16).
// REGISTER BUDGET (rounds 2-3 post-mortem): the backend's default heuristic
// targets 4 waves/EU = 128 unified regs/wave; our working set is ~250, so
// both (512,2) and plain (512) builds spilled ~120 dwords/thread to scratch
// (VGPR_Count=128, 12.7k cyc/step, VALUBusy 51% active). amdgpu_waves_per_eu
// min=1 raises the allocator budget to 512; actual use ~250 -> <=256 after
// granule rounding -> 2 waves/EU still physically resident. LDS 152KB caps
// at 1 block/CU regardless, so occupancy is unchanged by design.
__global__ __attribute__((amdgpu_flat_work_group_size(512, 512),
                          amdgpu_waves_per_eu(1, 2))) void lstm_mfma(
    const uint4* __restrict__ xg_frag, const uint4* __restrict__ whr,
    const uint4* __restrict__ whl, unsigned short* __restrict__ h16g) {
  int dir = blockIdx.x >> 1, bg = blockIdx.x & 1;
  int t = threadIdx.x;
  int lane = t & 63, w = t >> 6;
  int c = lane & 15, q = lane >> 4;

  __shared__ uint4 wlds[2 * 64 * 64];        // 128 KB: kt 6,7
  __shared__ uint4 wlds5[16 * 64];           // 16 KB: kt 5, nt 6,7
  __shared__ unsigned short hsw[16 * 256];   // 8 KB swizzled h

  for (int i = t; i < 8192; i += 512) wlds[i] = whl[(size_t)dir * 8192 + i];
  for (int i = t; i < 1024; i += 512) {
    int widx = i >> 7, sub = (i >> 6) & 1, l2 = i & 63;
    wlds5[i] = whr[((size_t)(dir * 6 + 5) * 64 + widx * 8 + 6 + sub) * 64 + l2];
  }
  for (int i = t; i < 2048; i += 512) ((unsigned int*)hsw)[i] = 0;

  uint4 wreg[46];
#pragma unroll
  for (int kt = 0; kt < 5; ++kt)
#pragma unroll
    for (int nt = 0; nt < 8; ++nt)
      wreg[kt * 8 + nt] =
          whr[((size_t)(dir * 6 + kt) * 64 + w * 8 + nt) * 64 + lane];
#pragma unroll
  for (int nt = 0; nt < 6; ++nt)
    wreg[40 + nt] = whr[((size_t)(dir * 6 + 5) * 64 + w * 8 + nt) * 64 + lane];

  float cst[8];
#pragma unroll
  for (int i = 0; i < 8; ++i) cst[i] = 0.f;

  const uint4* xgb =
      xg_frag + ((size_t)(dir * 1024 + bg * 512) * 32 + w * 4) * 64 + lane;
  unsigned short* hgb = h16g + (size_t)dir * 4194304 + bg * 16 + 4 * q;
  const int xk = (c & 7) << 3;

  __syncthreads();

#pragma unroll 1
  for (int s = 0; s < TT_LEN; ++s) {
    int tt = dir ? (TT_LEN - 1 - s) : s;
    const uint4* xp = xgb + (size_t)tt * 2048;
    uint4 xa = xp[0];
    uint4 xb = xp[64];
    f32x4 D[8];
#pragma unroll
    for (int nt = 0; nt < 8; ++nt) D[nt] = (f32x4){0.f, 0.f, 0.f, 0.f};
#pragma unroll
    for (int kt = 0; kt < 8; ++kt) {
      half8 A = *(const half8*)(hsw + (c * 256 + ((kt * 32 + q * 8) ^ xk)));
#pragma unroll
      for (int nt = 0; nt < 8; ++nt) {
        uint4 bw;
        if (kt < 5)
          bw = wreg[kt * 8 + nt];
        else if (kt == 5)
          bw = (nt < 6) ? wreg[40 + nt] : wlds5[(w * 2 + nt - 6) * 64 + lane];
        else
          bw = wlds[((kt - 6) * 64 + w * 8 + nt) * 64 + lane];
        D[nt] = __builtin_amdgcn_mfma_f32_16x16x32_f16(
            A, __builtin_bit_cast(half8, bw), D[nt], 0, 0, 0);
      }
    }
    __syncthreads();  // all A-reads done -> hsw writable
    uint4 xc = xp[128];
    uint4 xd = xp[192];
#pragma unroll
    for (int ph = 0; ph < 2; ++ph) {
      uint4 va = ph ? xc : xa;
      uint4 vb = ph ? xd : xb;
      float2 p0 = h2f(va.x), p1 = h2f(va.y), p2 = h2f(va.z), p3 = h2f(va.w);
      float2 p4 = h2f(vb.x), p5 = h2f(vb.y), p6 = h2f(vb.z), p7 = h2f(vb.w);
      float xi[4] = {p0.x, p0.y, p1.x, p1.y};
      float xf[4] = {p2.x, p2.y, p3.x, p3.y};
      float xgv[4] = {p4.x, p4.y, p5.x, p5.y};
      float xo[4] = {p6.x, p6.y, p7.x, p7.y};
      int u = w * 32 + ph * 16 + c;
      float hv[4];
#pragma unroll
      for (int r = 0; r < 4; ++r) {
        float I = sigm(D[ph * 4 + 0][r] + xi[r]);
        float F = sigm(D[ph * 4 + 1][r] + xf[r]);
        float G = tanh_f(D[ph * 4 + 2][r] + xgv[r]);
        float O = sigm(D[ph * 4 + 3][r] + xo[r]);
        float cn = F * cst[ph * 4 + r] + I * G;
        cst[ph * 4 + r] = cn;
        float h = O * tanh_f(cn);
        hv[r] = h;
        int m = 4 * q + r;
        hsw[m * 256 + (u ^ ((m & 7) << 3))] = f16b(h);
      }
      uint2 pk;
      pk.x = packh(hv[0], hv[1]);
      pk.y = packh(hv[2], hv[3]);
      *(uint2*)(hgb + ((size_t)tt * 8192 + u * 32)) = pk;  // fire-and-forget
    }
    __syncthreads();  // h ready for next step
  }
}

// ---------------- K3: scores = h . w_out (off the critical path) ----------
__global__ __launch_bounds__(64) void hscore(
    const unsigned short* __restrict__ h16g, const float* __restrict__ w_out,
    float* __restrict__ scores_part) {
  int dt = blockIdx.x;          // 0..1023 = dir*512 + t
  int dir = dt >> 9, tpos = dt & 511;
  int l = threadIdx.x;
  int b = l & 31, uh = l >> 5;
  const unsigned short* base =
      h16g + (((size_t)dir * 512 + tpos) * 256 + uh * 128) * 32 + b;
  const float* wo = w_out + dir * HH + uh * 128;
  float s = 0.f;
#pragma unroll 8
  for (int u = 0; u < 128; ++u) {
    _Float16 hv = __builtin_bit_cast(_Float16, base[(size_t)u * 32]);
    s += (float)hv * wo[u];
  }
  s += __shfl_down(s, 32, 64);
  if (uh == 0) scores_part[((size_t)dir * BB + b) * TT_LEN + tpos] = s;
}

// ---------------- K4: CRF fwd+bwd in PARALLEL WAVES ------------------------
__global__ __launch_bounds__(128) void dp3(const float* __restrict__ scores_part,
                                           const float* __restrict__ b_out,
                                           float* __restrict__ ast_g,
                                           float* __restrict__ bst_g,
                                           float* __restrict__ lzv) {
  int b = blockIdx.x;
  int l = threadIdx.x & 63;
  int w = threadIdx.x >> 6;
  const float* spf = scores_part + (size_t)b * TT_LEN;
  const float* spb = scores_part + (size_t)(BB + b) * TT_LEN;
  float bo = b_out[0];

  float ur[8];
#pragma unroll
  for (int i = 0; i < 8; ++i)
    ur[i] = (spf[i * 64 + l] + spb[i * 64 + l] + bo) * INV_TEMP;

  if (w == 0) {
    // ---------------- forward ----------------
    float* ast = ast_g + (size_t)b * TT_LEN * AST_STRIDE;
    int lm1 = (l + 63) & 63;
    float a0[3], a1[3];
    float u00 = __shfl(ur[0], 0, 64);
    a0[0] = (l == 1) ? (u00 + TRANS_T) : NEGF;
    a0[1] = NEGF;
    a0[2] = NEGF;
    a1[0] = (l == 0) ? 0.0f : NEGF;
    a1[1] = NEGF;
    a1[2] = NEGF;
    ast[l] = a0[0];
    ast[64 + l] = a0[1];
    if (l < 27) ast[128 + l] = a0[2];

#pragma unroll
    for (int ch = 0; ch < 8; ++ch) {
      float uc = ur[ch];
#pragma unroll 4
      for (int tt = (ch == 0 ? 1 : 0); tt < 64; ++tt) {
        int t = ch * 64 + tt;
        float u0t = __shfl(uc, tt, 64);
        float w0a = __shfl(a0[0], lm1, 64);
        float w1a = __shfl(a0[1], lm1, 64);
        float w2a = __shfl(a0[2], lm1, 64);
        float w0b = __shfl(a1[0], lm1, 64);
        float w1b = __shfl(a1[1], lm1, 64);
        float w2b = __shfl(a1[2], lm1, 64);
        float p0a = (l == 0) ? NEGF : w0a;
        float p1a = (l == 0) ? w0a : w1a;
        float p2a = (l == 0) ? w1a : w2a;
        float p0b = (l == 0) ? NEGF : w0b;
        float p1b = (l == 0) ? w0b : w1b;
        float p2b = (l == 0) ? w1b : w2b;
        float n00 = u0t + la(p0a + TRANS_T, p0b);
        float n01 = u0t + la(p1a + TRANS_T, p1b);
        float n02 = u0t + la(p2a + TRANS_T, p2b);
        float n10 = la(a0[0], a1[0]);
        float n11 = la(a0[1], a1[1]);
        float n12 = la(a0[2], a1[2]);
        a0[0] = n00;
        a0[1] = n01;
        a0[2] = (l < 27) ? n02 : NEGF;
        a1[0] = n10;
        a1[1] = n11;
        a1[2] = (l < 27) ? n12 : NEGF;
        float* astr = ast + (size_t)t * AST_STRIDE;
        astr[l] = a0[0];
        astr[64 + l] = a0[1];
        if (l < 27) astr[128 + l] = a0[2];
      }
    }
    // logZ
    float f00 = a0[0] + TRANS_T, f01 = a0[1] + TRANS_T, f02 = a0[2] + TRANS_T;
    float m = fmaxf(fmaxf(fmaxf(f00, f01), fmaxf(f02, a1[0])),
                    fmaxf(a1[1], a1[2]));
#pragma unroll
    for (int off = 32; off > 0; off >>= 1) m = fmaxf(m, __shfl_xor(m, off, 64));
    float es = __expf(f00 - m) + __expf(f01 - m) + __expf(f02 - m) +
               __expf(a1[0] - m) + __expf(a1[1] - m) + __expf(a1[2] - m);
#pragma unroll
    for (int off = 32; off > 0; off >>= 1) es += __shfl_xor(es, off, 64);
    if (l == 0) lzv[b] = m + __logf(es);
  } else {
    // ---------------- backward (independent of alpha) ----------------
    float* bst = bst_g + (size_t)b * TT_LEN * AST_STRIDE;
    int lp1 = (l + 1) & 63;
    float b0[3], b1[3];
    b0[0] = TRANS_T;
    b0[1] = TRANS_T;
    b0[2] = (l < 27) ? TRANS_T : NEGF;
    b1[0] = 0.0f;
    b1[1] = 0.0f;
    b1[2] = (l < 27) ? 0.0f : NEGF;
    {
      float* br = bst + (size_t)(TT_LEN - 1) * AST_STRIDE;
      br[l] = b0[0];
      br[64 + l] = b0[1];
      if (l < 27) br[128 + l] = b0[2];
    }
#pragma unroll
    for (int ch = 7; ch >= 0; --ch) {
      float uc = ur[ch];
#pragma unroll 4
      for (int tt = 63; tt >= (ch == 0 ? 1 : 0); --tt) {
        int t = ch * 64 + tt;
        float u0t = __shfl(uc, tt, 64);
        float w0 = __shfl(b0[0], lp1, 64);
        float w1 = __shfl(b0[1], lp1, 64);
        float w2 = __shfl(b0[2], lp1, 64);
        float x2 = (l == 63) ? NEGF : w2;
        float x1 = (l == 63) ? w2 : w1;
        float x0 = (l == 63) ? w1 : w0;
        float nb00 = la(u0t + TRANS_T + x0, b1[0]);
        float nb01 = la(u0t + TRANS_T + x1, b1[1]);
        float nb02 = la(u0t + TRANS_T + x2, b1[2]);
        float nb10 = la(u0t + x0, b1[0]);
        float nb11 = la(u0t + x1, b1[1]);
        float nb12 = la(u0t + x2, b1[2]);
        b0[0] = nb00;
        b0[1] = nb01;
        b0[2] = (l < 27) ? nb02 : NEGF;
        b1[0] = nb10;
        b1[1] = nb11;
        b1[2] = (l < 27) ? nb12 : NEGF;
        float* br = bst + (size_t)(t - 1) * AST_STRIDE;
        br[l] = b0[0];
        br[64 + l] = b0[1];
        if (l < 27) br[128 + l] = b0[2];
      }
    }
  }
}

// ---------------- K5: marginals, fully parallel ----------------------------
__global__ __launch_bounds__(256) void marg(const float* __restrict__ ast_g,
                                            const float* __restrict__ bst_g,
                                            const float* __restrict__ lzv,
                                            float* __restrict__ out) {
  int row = blockIdx.x * 4 + (threadIdx.x >> 6);
  int l = threadIdx.x & 63;
  int b = row >> 9;
  const float* ar = ast_g + (size_t)row * AST_STRIDE;
  const float* br = bst_g + (size_t)row * AST_STRIDE;
  float lz = lzv[b];
  float s = __expf(ar[l] + br[l] - lz) + __expf(ar[64 + l] + br[64 + l] - lz) +
            ((l < 27) ? __expf(ar[128 + l] + br[128 + l] - lz) : 0.0f);
#pragma unroll
  for (int off = 32; off > 0; off >>= 1) s += __shfl_xor(s, off, 64);
  if (l == 0) out[row] = s;
}

// ---------------------------------------------------------------------------
extern "C" void kernel_launch(void* const* d_in, const int* in_sizes, int n_in,
                              void* d_out, int out_size, void* d_ws, size_t ws_size,
                              hipStream_t stream) {
  const int* x = (const int*)d_in[0];
  const float* embed = (const float*)d_in[3];
  const float* wi_f = (const float*)d_in[4];
  const float* wh_f = (const float*)d_in[5];
  const float* bf = (const float*)d_in[6];
  const float* wi_b = (const float*)d_in[7];
  const float* wh_b = (const float*)d_in[8];
  const float* bbias = (const float*)d_in[9];
  const float* w_out = (const float*)d_in[10];
  const float* b_out = (const float*)d_in[11];

  float* ws = (float*)d_ws;
  float* b_p = ws;                                            // 2048 f32
  unsigned int* wi_frag = (unsigned int*)(b_p + 2 * G4);      // 327680 dw
  uint4* whr = (uint4*)(wi_frag + 2 * 64 * 10 * 64 * 4);      // 49152 uint4
  uint4* whl = whr + 49152;                                   // 16384 uint4
  uint4* emb_frag = whl + 16384;                              // 655360 uint4
  uint4* xg_frag = emb_frag + 655360;                         // 4194304 uint4
  unsigned short* h16g = (unsigned short*)(xg_frag + 4194304);  // 8388608 us
  float* scores_part = (float*)(h16g + 8388608);              // 32768 f32
  float* lzv = scores_part + 2 * BB * TT_LEN;                 // 32 (+pad)
  float* ast_g = lzv + 64;                                    // 32*512*159 f32
  // bst aliases emb_frag (dead after xg_mfma): 10.42 MB fits in 10.49 MB
  float* bst_g = (float*)emb_frag;
  float* outp = (float*)d_out;

  prep_weights<<<256, 256, 0, stream>>>(wi_f, wi_b, wh_f, wh_b, bf, bbias,
                                        wi_frag, b_p, whr, whl);
  gather_emb<<<(BB * TT_LEN) / 16, 256, 0, stream>>>(x, embed, emb_frag);
  dim3 g1(16, 256, 2);
  xg_mfma<<<g1, 256, 0, stream>>>(emb_frag, (const uint4*)wi_frag, b_p, xg_frag);
  lstm_mfma<<<4, 512, 0, stream>>>(xg_frag, whr, whl, h16g);
  hscore<<<2 * TT_LEN, 64, 0, stream>>>(h16g, w_out, scores_part);
  dp3<<<BB, 128, 0, stream>>>(scores_part, b_out, ast_g, bst_g, lzv);
  marg<<<(BB * TT_LEN) / 4, 256, 0, stream>>>(ast_g, bst_g, lzv, outp);
}

// Round 5
// 2898.157 us; speedup vs baseline: 1.0730x; 1.0722x over previous
//
#include <hip/hip_runtime.h>
#include <math.h>

// Problem constants (reference: B,T,V,E,H = 32,512,32000,300,256)
#define BB 32
#define TT_LEN 512
#define EE 300
#define HH 256
#define G4 1024          // 4*H
#define CMAX 155         // int(round(0.3*512))+1
#define TRANS_T 10.0f    // TRANSITION/TEMP
#define NEGF -1.0e9f
#define INV_TEMP 100.0f  // 1/TEMP
#define AST_STRIDE 159   // slot-2 accesses predicated l<27 (max off 154)

typedef _Float16 half2v __attribute__((ext_vector_type(2)));
typedef _Float16 half8 __attribute__((ext_vector_type(8)));
typedef float f32x4 __attribute__((ext_vector_type(4)));

__device__ __forceinline__ float la(float x, float y) {
  float m = fmaxf(x, y);
  float d = fminf(x, y) - m;
  return m + __logf(1.0f + __expf(d));
}

__device__ __forceinline__ float sigm(float x) {
  return 1.0f / (1.0f + __expf(-x));
}

__device__ __forceinline__ float tanh_f(float x) {
  x = fminf(fmaxf(x, -15.f), 15.f);
  float e = __expf(2.f * x);
  return (e - 1.f) * __frcp_rn(e + 1.f);
}

__device__ __forceinline__ unsigned int packh(float a, float b) {
  half2v hp;
  hp.x = (_Float16)a;
  hp.y = (_Float16)b;
  return __builtin_bit_cast(unsigned int, hp);
}

__device__ __forceinline__ float2 h2f(unsigned int d) {
  half2v h = __builtin_bit_cast(half2v, d);
  return make_float2((float)h.x, (float)h.y);
}

// column mapping: gate-column n (0..1023) -> source column g*HH+u with
// g = gate type, u = unit: n-tile nb covers (g = nb&3, ugroup = nb>>2),
// u = (nb>>2)*16 + (n&15). Used consistently by wi_frag, b_p, whn.
__device__ __forceinline__ int nmap_col(int n) {
  int g = (n >> 4) & 3;
  int u = (n >> 7) * 32 + ((n >> 6) & 1) * 16 + (n & 15);
  return g * HH + u;
}

// ---------------- K0: weight prep ------------------------------------------
// wi_frag: B-fragments for xg_mfma (remapped columns)
// whn: Wh B-fragments [dir][kt(8)][nb(64)][lane(64)] uint4
// also zeroes the exchange flags (runs before lstm every graph replay).
__global__ void prep_weights(const float* wi_f, const float* wi_b,
                             const float* wh_f, const float* wh_b,
                             const float* b_f, const float* b_b,
                             unsigned int* wi_frag, float* b_p,
                             uint4* whn, int* flags) {
  int idx = blockIdx.x * blockDim.x + threadIdx.x;
  int stride = gridDim.x * blockDim.x;
  for (int i = idx; i < 128; i += stride) flags[i] = 0;
  for (int i = idx; i < 2 * 64 * 10 * 64 * 4; i += stride) {
    int u4 = i >> 2, d = i & 3;
    int lane = u4 & 63;
    int kk = (u4 >> 6) % 10;
    int nb = (u4 / 640) & 63;
    int dir = u4 / (640 * 64);
    int l15 = lane & 15, quad = lane >> 4;
    int col = nmap_col(nb * 16 + l15);
    int k0 = kk * 32 + quad * 8 + 2 * d;
    const float* src = dir ? wi_b : wi_f;
    float v0 = (k0 < EE) ? src[(size_t)k0 * G4 + col] : 0.0f;
    float v1 = (k0 + 1 < EE) ? src[(size_t)(k0 + 1) * G4 + col] : 0.0f;
    wi_frag[i] = packh(v0, v1);
  }
  for (int i = idx; i < 2 * 8 * 64 * 64; i += stride) {
    int lane = i & 63;
    int nb = (i >> 6) & 63;
    int kt = (i >> 12) & 7;
    int dir = i >> 15;
    int c = lane & 15, q = lane >> 4;
    int col = nmap_col(nb * 16 + c);
    int k0 = kt * 32 + q * 8;
    const float* src = dir ? wh_b : wh_f;
    uint4 o;
    o.x = packh(src[(size_t)(k0 + 0) * G4 + col], src[(size_t)(k0 + 1) * G4 + col]);
    o.y = packh(src[(size_t)(k0 + 2) * G4 + col], src[(size_t)(k0 + 3) * G4 + col]);
    o.z = packh(src[(size_t)(k0 + 4) * G4 + col], src[(size_t)(k0 + 5) * G4 + col]);
    o.w = packh(src[(size_t)(k0 + 6) * G4 + col], src[(size_t)(k0 + 7) * G4 + col]);
    whn[i] = o;  // i == ((dir*8+kt)*64+nb)*64+lane
  }
  for (int i = idx; i < 2 * G4; i += stride) {
    int dir = i / G4;
    int j = i % G4;
    const float* src = dir ? b_b : b_f;
    b_p[i] = src[nmap_col(j)];
  }
}

// ---------------- K_emb: gather -> A-fragment layout -----------------------
// m-tile mblk = bg*512 + t holds 16 BATCH rows (bg*16..bg*16+15) at time t.
__global__ void gather_emb(const int* x, const float* embed, uint4* emb_frag) {
  int mblk = blockIdx.x;
  int t = threadIdx.x;
  int bg = mblk >> 9, tloc = mblk & 511;
  __shared__ int xs[16];
  if (t < 16) xs[t] = x[(bg * 16 + t) * TT_LEN + tloc];
  __syncthreads();
  for (int slot = t; slot < 640; slot += 256) {
    int kk = slot >> 6;
    int lane = slot & 63;
    int l15 = lane & 15, quad = lane >> 4;
    int row = xs[l15];
    int kbase = kk * 32 + quad * 8;
    const float* src = embed + (size_t)row * EE;
    float v[8];
#pragma unroll
    for (int e = 0; e < 8; ++e) v[e] = (kbase + e < EE) ? src[kbase + e] : 0.0f;
    uint4 o;
    o.x = packh(v[0], v[1]);
    o.y = packh(v[2], v[3]);
    o.z = packh(v[4], v[5]);
    o.w = packh(v[6], v[7]);
    emb_frag[(size_t)(mblk * 10 + kk) * 64 + lane] = o;
  }
}

// ---------------- K1: xg = emb @ wi^T + b, stored as f16 D-fragments -------
__global__ __launch_bounds__(256) void xg_mfma(
    const uint4* __restrict__ emb_frag, const uint4* __restrict__ wi_frag,
    const float* __restrict__ b_p, uint4* __restrict__ xg_frag) {
  int dir = blockIdx.z;
  int w = threadIdx.x >> 6;
  int lane = threadIdx.x & 63;
  int l15 = lane & 15;
  int mblk = blockIdx.y * 4 + w;

  const uint4* abase = emb_frag + (size_t)mblk * 10 * 64 + lane;
  f32x4 acc[4];
#pragma unroll
  for (int nt = 0; nt < 4; ++nt) acc[nt] = (f32x4){0.f, 0.f, 0.f, 0.f};

#pragma unroll
  for (int kk = 0; kk < 10; ++kk) {
    half8 a = __builtin_bit_cast(half8, abase[kk * 64]);
#pragma unroll
    for (int nt = 0; nt < 4; ++nt) {
      int nb = blockIdx.x * 4 + nt;
      half8 b = __builtin_bit_cast(
          half8, wi_frag[((size_t)(dir * 64 + nb) * 10 + kk) * 64 + lane]);
      acc[nt] = __builtin_amdgcn_mfma_f32_16x16x32_f16(a, b, acc[nt], 0, 0, 0);
    }
  }
#pragma unroll
  for (int ntp = 0; ntp < 2; ++ntp) {
    float bA = b_p[dir * G4 + (blockIdx.x * 4 + 2 * ntp) * 16 + l15];
    float bB = b_p[dir * G4 + (blockIdx.x * 4 + 2 * ntp + 1) * 16 + l15];
    f32x4 aA = acc[2 * ntp], aB = acc[2 * ntp + 1];
    uint4 o;
    o.x = packh(aA[0] + bA, aA[1] + bA);
    o.y = packh(aA[2] + bA, aA[3] + bA);
    o.z = packh(aB[0] + bB, aB[1] + bB);
    o.w = packh(aB[2] + bB, aB[3] + bB);
    xg_frag[((size_t)(dir * 1024 + mblk) * 32 + blockIdx.x * 2 + ntp) * 64 + lane] = o;
  }
}

// ---------------- K2: batched-MFMA LSTM, N-split across block pairs --------
// 8 blocks = (dir, bg, nh). Each block: 16 batch recurrences, 128 units
// (its N-half, all 4 gates). Wh slice = 256KB: kt_own (4 K-tiles) in regs
// (16 frags = 64 VGPR), kt_partner in LDS (128KB). This is the design that
// FITS the hard 128-reg cap (rounds 2-4: 184-dw-in-reg design spilled ~120dw
// at the unavoidable 128 budget -> 12.7k cyc/step).
// h halves exchanged per step via agent-scope atomics (double-buffered
// parity) + release/acquire flag; own-half MFMAs run under the exchange
// latency. Spin guarded: a handshake bug degrades, never hangs.
__global__ __launch_bounds__(512) void lstm_mfma(
    const uint4* __restrict__ xg_frag, const uint4* __restrict__ whn,
    unsigned short* __restrict__ h16g, unsigned int* __restrict__ hexb,
    int* __restrict__ flags) {
  int bid = blockIdx.x;  // dir*4 + bg*2 + nh
  int dir = bid >> 2, bg = (bid >> 1) & 1, nh = bid & 1;
  int pbid = bid ^ 1;
  int t = threadIdx.x, lane = t & 63, w = t >> 6;
  int c = lane & 15, q = lane >> 4;

  __shared__ uint4 wlds[4 * 32 * 64];       // 128 KB: partner-kt weights
  __shared__ unsigned short hsw[16 * 256];  // 8 KB swizzled h (full 256 units)

  const int ktreg = 4 * nh;        // K-tiles of OWN units (h we produce)
  const int ktlds = 4 * (1 - nh);  // K-tiles of partner units
  const int pbase = 128 * (1 - nh);

  // stage LDS weights: kt = ktlds..+3, nb = 32nh..+31
  for (int i = t; i < 8192; i += 512) {
    int kk = i >> 11, nbl = (i >> 6) & 31, l2 = i & 63;
    wlds[i] = whn[(((size_t)dir * 8 + ktlds + kk) * 64 + 32 * nh + nbl) * 64 + l2];
  }
  for (int i = t; i < 2048; i += 512) ((unsigned int*)hsw)[i] = 0;

  uint4 wreg[16];
#pragma unroll
  for (int kk = 0; kk < 4; ++kk)
#pragma unroll
    for (int g = 0; g < 4; ++g)
      wreg[kk * 4 + g] =
          whn[(((size_t)dir * 8 + ktreg + kk) * 64 + 32 * nh + w * 4 + g) * 64 + lane];

  float cst[4] = {0.f, 0.f, 0.f, 0.f};
  const int u = nh * 128 + w * 16 + c;  // unit this thread owns
  const int xk = (c & 7) << 3;

  const uint4* xgb =
      xg_frag + ((size_t)(dir * 1024 + bg * 512) * 32 + nh * 16 + w * 2) * 64 + lane;
  unsigned short* hgb =
      h16g + (size_t)dir * 4194304 + (size_t)u * 32 + bg * 16 + 4 * q;
  int* flagp = &flags[pbid * 16];
  int* flagm = &flags[bid * 16];

  __syncthreads();

#pragma unroll 1
  for (int s = 0; s < TT_LEN; ++s) {
    int tt = dir ? (TT_LEN - 1 - s) : s;
    const uint4* xp = xgb + (size_t)tt * 2048;
    uint4 xA = xp[0];
    uint4 xB = xp[64];

    // ---- fetch partner h(s-1) (latency hidden under own-kt MFMAs) ----
    unsigned long long stg = 0;
    if (s > 0) {
      int guard = 0;
      while (__hip_atomic_load(flagp, __ATOMIC_ACQUIRE,
                               __HIP_MEMORY_SCOPE_AGENT) < s) {
        __builtin_amdgcn_s_sleep(2);
        if (++guard > (1 << 17)) break;  // safety valve: degrade, don't hang
      }
      const unsigned long long* hex64 =
          (const unsigned long long*)(hexb + (size_t)(pbid * 2 + ((s - 1) & 1)) * 1024);
      stg = __hip_atomic_load(hex64 + (t >> 5) * 32 + (t & 31),
                              __ATOMIC_RELAXED, __HIP_MEMORY_SCOPE_AGENT);
    }

    f32x4 D[4];
#pragma unroll
    for (int g = 0; g < 4; ++g) D[g] = (f32x4){0.f, 0.f, 0.f, 0.f};

    // ---- phase 1: own-kt MFMAs, B from registers ----
#pragma unroll
    for (int kk = 0; kk < 4; ++kk) {
      half8 A = *(const half8*)(hsw + (c * 256 + (((ktreg + kk) * 32 + q * 8) ^ xk)));
#pragma unroll
      for (int g = 0; g < 4; ++g)
        D[g] = __builtin_amdgcn_mfma_f32_16x16x32_f16(
            A, __builtin_bit_cast(half8, wreg[kk * 4 + g]), D[g], 0, 0, 0);
    }

    // ---- stage partner h into hsw (disjoint rows from phase-1 reads) ----
    if (s > 0) {
      int m = t >> 5, j = t & 31;
      int pu = pbase + 4 * j;
      *(unsigned long long*)((char*)hsw + m * 512 + 2 * (pu ^ ((m & 7) << 3))) = stg;
    }
    __syncthreads();

    // ---- phase 2: partner-kt MFMAs, B from LDS ----
#pragma unroll
    for (int kk = 0; kk < 4; ++kk) {
      half8 A = *(const half8*)(hsw + (c * 256 + (((ktlds + kk) * 32 + q * 8) ^ xk)));
#pragma unroll
      for (int g = 0; g < 4; ++g)
        D[g] = __builtin_amdgcn_mfma_f32_16x16x32_f16(
            A, __builtin_bit_cast(half8, wlds[kk * 2048 + (w * 4 + g) * 64 + lane]),
            D[g], 0, 0, 0);
    }

    // ---- elementwise ----
    float2 p0 = h2f(xA.x), p1 = h2f(xA.y), p2 = h2f(xA.z), p3 = h2f(xA.w);
    float2 p4 = h2f(xB.x), p5 = h2f(xB.y), p6 = h2f(xB.z), p7 = h2f(xB.w);
    float xi[4] = {p0.x, p0.y, p1.x, p1.y};
    float xf[4] = {p2.x, p2.y, p3.x, p3.y};
    float xgv[4] = {p4.x, p4.y, p5.x, p5.y};
    float xo[4] = {p6.x, p6.y, p7.x, p7.y};
    float hv[4];
#pragma unroll
    for (int r = 0; r < 4; ++r) {
      float I = sigm(D[0][r] + xi[r]);
      float F = sigm(D[1][r] + xf[r]);
      float G = tanh_f(D[2][r] + xgv[r]);
      float O = sigm(D[3][r] + xo[r]);
      float cn = F * cst[r] + I * G;
      cst[r] = cn;
      hv[r] = O * tanh_f(cn);
    }
    // publish h: LDS (own half, for next step) + global exchange + h16g
    unsigned int* hexm = hexb + (size_t)(bid * 2 + (s & 1)) * 1024;
#pragma unroll
    for (int r = 0; r < 4; ++r) {
      float hn = __shfl_down(hv[r], 1, 64);
      if (!(c & 1)) {
        unsigned int pk = packh(hv[r], hn);
        int m = 4 * q + r;
        ((unsigned int*)hsw)[(m * 256 + (u ^ ((m & 7) << 3))) >> 1] = pk;
        __hip_atomic_store(hexm + m * 64 + w * 8 + (c >> 1), pk,
                           __ATOMIC_RELAXED, __HIP_MEMORY_SCOPE_AGENT);
      }
    }
    uint2 pk2;
    pk2.x = packh(hv[0], hv[1]);
    pk2.y = packh(hv[2], hv[3]);
    *(uint2*)(hgb + (size_t)tt * 8192) = pk2;  // for hscore

    __syncthreads();  // drains all stores (vmcnt) + hsw writes visible
    if (t == 0)
      __hip_atomic_store(flagm, s + 1, __ATOMIC_RELEASE, __HIP_MEMORY_SCOPE_AGENT);
  }
}

// ---------------- K3: scores = h . w_out (off the critical path) ----------
__global__ __launch_bounds__(64) void hscore(
    const unsigned short* __restrict__ h16g, const float* __restrict__ w_out,
    float* __restrict__ scores_part) {
  int dt = blockIdx.x;          // 0..1023 = dir*512 + t
  int dir = dt >> 9, tpos = dt & 511;
  int l = threadIdx.x;
  int b = l & 31, uh = l >> 5;
  const unsigned short* base =
      h16g + (((size_t)dir * 512 + tpos) * 256 + uh * 128) * 32 + b;
  const float* wo = w_out + dir * HH + uh * 128;
  float s = 0.f;
#pragma unroll 8
  for (int u = 0; u < 128; ++u) {
    _Float16 hv = __builtin_bit_cast(_Float16, base[(size_t)u * 32]);
    s += (float)hv * wo[u];
  }
  s += __shfl_down(s, 32, 64);
  if (uh == 0) scores_part[((size_t)dir * BB + b) * TT_LEN + tpos] = s;
}

// ---------------- K4: CRF fwd+bwd in PARALLEL WAVES ------------------------
__global__ __launch_bounds__(128) void dp3(const float* __restrict__ scores_part,
                                           const float* __restrict__ b_out,
                                           float* __restrict__ ast_g,
                                           float* __restrict__ bst_g,
                                           float* __restrict__ lzv) {
  int b = blockIdx.x;
  int l = threadIdx.x & 63;
  int w = threadIdx.x >> 6;
  const float* spf = scores_part + (size_t)b * TT_LEN;
  const float* spb = scores_part + (size_t)(BB + b) * TT_LEN;
  float bo = b_out[0];

  float ur[8];
#pragma unroll
  for (int i = 0; i < 8; ++i)
    ur[i] = (spf[i * 64 + l] + spb[i * 64 + l] + bo) * INV_TEMP;

  if (w == 0) {
    float* ast = ast_g + (size_t)b * TT_LEN * AST_STRIDE;
    int lm1 = (l + 63) & 63;
    float a0[3], a1[3];
    float u00 = __shfl(ur[0], 0, 64);
    a0[0] = (l == 1) ? (u00 + TRANS_T) : NEGF;
    a0[1] = NEGF;
    a0[2] = NEGF;
    a1[0] = (l == 0) ? 0.0f : NEGF;
    a1[1] = NEGF;
    a1[2] = NEGF;
    ast[l] = a0[0];
    ast[64 + l] = a0[1];
    if (l < 27) ast[128 + l] = a0[2];

#pragma unroll
    for (int ch = 0; ch < 8; ++ch) {
      float uc = ur[ch];
#pragma unroll 4
      for (int tt = (ch == 0 ? 1 : 0); tt < 64; ++tt) {
        int t = ch * 64 + tt;
        float u0t = __shfl(uc, tt, 64);
        float w0a = __shfl(a0[0], lm1, 64);
        float w1a = __shfl(a0[1], lm1, 64);
        float w2a = __shfl(a0[2], lm1, 64);
        float w0b = __shfl(a1[0], lm1, 64);
        float w1b = __shfl(a1[1], lm1, 64);
        float w2b = __shfl(a1[2], lm1, 64);
        float p0a = (l == 0) ? NEGF : w0a;
        float p1a = (l == 0) ? w0a : w1a;
        float p2a = (l == 0) ? w1a : w2a;
        float p0b = (l == 0) ? NEGF : w0b;
        float p1b = (l == 0) ? w0b : w1b;
        float p2b = (l == 0) ? w1b : w2b;
        float n00 = u0t + la(p0a + TRANS_T, p0b);
        float n01 = u0t + la(p1a + TRANS_T, p1b);
        float n02 = u0t + la(p2a + TRANS_T, p2b);
        float n10 = la(a0[0], a1[0]);
        float n11 = la(a0[1], a1[1]);
        float n12 = la(a0[2], a1[2]);
        a0[0] = n00;
        a0[1] = n01;
        a0[2] = (l < 27) ? n02 : NEGF;
        a1[0] = n10;
        a1[1] = n11;
        a1[2] = (l < 27) ? n12 : NEGF;
        float* astr = ast + (size_t)t * AST_STRIDE;
        astr[l] = a0[0];
        astr[64 + l] = a0[1];
        if (l < 27) astr[128 + l] = a0[2];
      }
    }
    float f00 = a0[0] + TRANS_T, f01 = a0[1] + TRANS_T, f02 = a0[2] + TRANS_T;
    float m = fmaxf(fmaxf(fmaxf(f00, f01), fmaxf(f02, a1[0])),
                    fmaxf(a1[1], a1[2]));
#pragma unroll
    for (int off = 32; off > 0; off >>= 1) m = fmaxf(m, __shfl_xor(m, off, 64));
    float es = __expf(f00 - m) + __expf(f01 - m) + __expf(f02 - m) +
               __expf(a1[0] - m) + __expf(a1[1] - m) + __expf(a1[2] - m);
#pragma unroll
    for (int off = 32; off > 0; off >>= 1) es += __shfl_xor(es, off, 64);
    if (l == 0) lzv[b] = m + __logf(es);
  } else {
    float* bst = bst_g + (size_t)b * TT_LEN * AST_STRIDE;
    int lp1 = (l + 1) & 63;
    float b0[3], b1[3];
    b0[0] = TRANS_T;
    b0[1] = TRANS_T;
    b0[2] = (l < 27) ? TRANS_T : NEGF;
    b1[0] = 0.0f;
    b1[1] = 0.0f;
    b1[2] = (l < 27) ? 0.0f : NEGF;
    {
      float* br = bst + (size_t)(TT_LEN - 1) * AST_STRIDE;
      br[l] = b0[0];
      br[64 + l] = b0[1];
      if (l < 27) br[128 + l] = b0[2];
    }
#pragma unroll
    for (int ch = 7; ch >= 0; --ch) {
      float uc = ur[ch];
#pragma unroll 4
      for (int tt = 63; tt >= (ch == 0 ? 1 : 0); --tt) {
        int t = ch * 64 + tt;
        float u0t = __shfl(uc, tt, 64);
        float w0 = __shfl(b0[0], lp1, 64);
        float w1 = __shfl(b0[1], lp1, 64);
        float w2 = __shfl(b0[2], lp1, 64);
        float x2 = (l == 63) ? NEGF : w2;
        float x1 = (l == 63) ? w2 : w1;
        float x0 = (l == 63) ? w1 : w0;
        float nb00 = la(u0t + TRANS_T + x0, b1[0]);
        float nb01 = la(u0t + TRANS_T + x1, b1[1]);
        float nb02 = la(u0t + TRANS_T + x2, b1[2]);
        float nb10 = la(u0t + x0, b1[0]);
        float nb11 = la(u0t + x1, b1[1]);
        float nb12 = la(u0t + x2, b1[2]);
        b0[0] = nb00;
        b0[1] = nb01;
        b0[2] = (l < 27) ? nb02 : NEGF;
        b1[0] = nb10;
        b1[1] = nb11;
        b1[2] = (l < 27) ? nb12 : NEGF;
        float* br = bst + (size_t)(t - 1) * AST_STRIDE;
        br[l] = b0[0];
        br[64 + l] = b0[1];
        if (l < 27) br[128 + l] = b0[2];
      }
    }
  }
}

// ---------------- K5: marginals, fully parallel ----------------------------
__global__ __launch_bounds__(256) void marg(const float* __restrict__ ast_g,
                                            const float* __restrict__ bst_g,
                                            const float* __restrict__ lzv,
                                            float* __restrict__ out) {
  int row = blockIdx.x * 4 + (threadIdx.x >> 6);
  int l = threadIdx.x & 63;
  int b = row >> 9;
  const float* ar = ast_g + (size_t)row * AST_STRIDE;
  const float* br = bst_g + (size_t)row * AST_STRIDE;
  float lz = lzv[b];
  float s = __expf(ar[l] + br[l] - lz) + __expf(ar[64 + l] + br[64 + l] - lz) +
            ((l < 27) ? __expf(ar[128 + l] + br[128 + l] - lz) : 0.0f);
#pragma unroll
  for (int off = 32; off > 0; off >>= 1) s += __shfl_xor(s, off, 64);
  if (l == 0) out[row] = s;
}

// ---------------------------------------------------------------------------
extern "C" void kernel_launch(void* const* d_in, const int* in_sizes, int n_in,
                              void* d_out, int out_size, void* d_ws, size_t ws_size,
                              hipStream_t stream) {
  const int* x = (const int*)d_in[0];
  const float* embed = (const float*)d_in[3];
  const float* wi_f = (const float*)d_in[4];
  const float* wh_f = (const float*)d_in[5];
  const float* bf = (const float*)d_in[6];
  const float* wi_b = (const float*)d_in[7];
  const float* wh_b = (const float*)d_in[8];
  const float* bbias = (const float*)d_in[9];
  const float* w_out = (const float*)d_in[10];
  const float* b_out = (const float*)d_in[11];

  float* ws = (float*)d_ws;
  float* b_p = ws;                                            // 2048 f32
  unsigned int* wi_frag = (unsigned int*)(b_p + 2 * G4);      // 327680 dw
  uint4* whn = (uint4*)(wi_frag + 2 * 64 * 10 * 64 * 4);      // 65536 uint4
  uint4* emb_frag = whn + 65536;                              // 655360 uint4
  uint4* xg_frag = emb_frag + 655360;                         // 4194304 uint4
  unsigned short* h16g = (unsigned short*)(xg_frag + 4194304);  // 8388608 us
  float* scores_part = (float*)(h16g + 8388608);              // 32768 f32
  float* lzv = scores_part + 2 * BB * TT_LEN;                 // 32 (+pad)
  float* ast_g = lzv + 64;                                    // 32*512*159 f32
  unsigned int* hexb = (unsigned int*)(ast_g + (size_t)BB * TT_LEN * AST_STRIDE);
  int* flags = (int*)(hexb + 16384);                          // 128 ints
  // bst aliases emb_frag (dead after xg_mfma): 10.42 MB fits in 10.49 MB
  float* bst_g = (float*)emb_frag;
  float* outp = (float*)d_out;

  prep_weights<<<256, 256, 0, stream>>>(wi_f, wi_b, wh_f, wh_b, bf, bbias,
                                        wi_frag, b_p, whn, flags);
  gather_emb<<<(BB * TT_LEN) / 16, 256, 0, stream>>>(x, embed, emb_frag);
  dim3 g1(16, 256, 2);
  xg_mfma<<<g1, 256, 0, stream>>>(emb_frag, (const uint4*)wi_frag, b_p, xg_frag);
  lstm_mfma<<<8, 512, 0, stream>>>(xg_frag, whn, h16g, hexb, flags);
  hscore<<<2 * TT_LEN, 64, 0, stream>>>(h16g, w_out, scores_part);
  dp3<<<BB, 128, 0, stream>>>(scores_part, b_out, ast_g, bst_g, lzv);
  marg<<<(BB * TT_LEN) / 4, 256, 0, stream>>>(ast_g, bst_g, lzv, outp);
}

// Round 7
// 2715.333 us; speedup vs baseline: 1.1453x; 1.0673x over previous
//
#include <hip/hip_runtime.h>
#include <math.h>

// Problem constants (reference: B,T,V,E,H = 32,512,32000,300,256)
#define BB 32
#define TT_LEN 512
#define EE 300
#define HH 256
#define G4 1024          // 4*H
#define CMAX 155         // int(round(0.3*512))+1
#define TRANS_T 10.0f    // TRANSITION/TEMP
#define NEGF -1.0e9f
#define INV_TEMP 100.0f  // 1/TEMP
#define AST_STRIDE 159   // slot-2 accesses predicated l<27 (max off 154)

typedef _Float16 half2v __attribute__((ext_vector_type(2)));
typedef _Float16 half8 __attribute__((ext_vector_type(8)));
typedef float f32x4 __attribute__((ext_vector_type(4)));

__device__ __forceinline__ float la(float x, float y) {
  float m = fmaxf(x, y);
  float d = fminf(x, y) - m;
  return m + __logf(1.0f + __expf(d));
}

__device__ __forceinline__ float sigm(float x) {
  return 1.0f / (1.0f + __expf(-x));
}

__device__ __forceinline__ float tanh_f(float x) {
  x = fminf(fmaxf(x, -15.f), 15.f);
  float e = __expf(2.f * x);
  return (e - 1.f) * __frcp_rn(e + 1.f);
}

__device__ __forceinline__ unsigned int packh(float a, float b) {
  half2v hp;
  hp.x = (_Float16)a;
  hp.y = (_Float16)b;
  return __builtin_bit_cast(unsigned int, hp);
}

__device__ __forceinline__ float2 h2f(unsigned int d) {
  half2v h = __builtin_bit_cast(half2v, d);
  return make_float2((float)h.x, (float)h.y);
}

__device__ __forceinline__ unsigned short f16b(float x) {
  _Float16 h = (_Float16)x;
  return __builtin_bit_cast(unsigned short, h);
}

// column mapping: gate-column n (0..1023) -> source column g*HH+u with
// g = gate type (i,f,g,o), u = unit. nb = [ug3][ug1][g2]: gate = nb&3,
// unit-group = nb>>2 (16 units). Thread (wave w, lane c) <-> unit w*16+c.
__device__ __forceinline__ int nmap_col(int n) {
  int g = (n >> 4) & 3;
  int u = (n >> 7) * 32 + ((n >> 6) & 1) * 16 + (n & 15);
  return g * HH + u;
}

// ---------------- K0: weight prep ------------------------------------------
// wi_frag: B-fragments for xg_mfma (remapped columns)
// whn: Wh B-fragments [dir][kt(8)][nb(64)][lane(64)] uint4
__global__ void prep_weights(const float* wi_f, const float* wi_b,
                             const float* wh_f, const float* wh_b,
                             const float* b_f, const float* b_b,
                             unsigned int* wi_frag, float* b_p, uint4* whn) {
  int idx = blockIdx.x * blockDim.x + threadIdx.x;
  int stride = gridDim.x * blockDim.x;
  for (int i = idx; i < 2 * 64 * 10 * 64 * 4; i += stride) {
    int u4 = i >> 2, d = i & 3;
    int lane = u4 & 63;
    int kk = (u4 >> 6) % 10;
    int nb = (u4 / 640) & 63;
    int dir = u4 / (640 * 64);
    int l15 = lane & 15, quad = lane >> 4;
    int col = nmap_col(nb * 16 + l15);
    int k0 = kk * 32 + quad * 8 + 2 * d;
    const float* src = dir ? wi_b : wi_f;
    float v0 = (k0 < EE) ? src[(size_t)k0 * G4 + col] : 0.0f;
    float v1 = (k0 + 1 < EE) ? src[(size_t)(k0 + 1) * G4 + col] : 0.0f;
    wi_frag[i] = packh(v0, v1);
  }
  for (int i = idx; i < 2 * 8 * 64 * 64; i += stride) {
    int lane = i & 63;
    int nb = (i >> 6) & 63;
    int kt = (i >> 12) & 7;
    int dir = i >> 15;
    int c = lane & 15, q = lane >> 4;
    int col = nmap_col(nb * 16 + c);
    int k0 = kt * 32 + q * 8;
    const float* src = dir ? wh_b : wh_f;
    uint4 o;
    o.x = packh(src[(size_t)(k0 + 0) * G4 + col], src[(size_t)(k0 + 1) * G4 + col]);
    o.y = packh(src[(size_t)(k0 + 2) * G4 + col], src[(size_t)(k0 + 3) * G4 + col]);
    o.z = packh(src[(size_t)(k0 + 4) * G4 + col], src[(size_t)(k0 + 5) * G4 + col]);
    o.w = packh(src[(size_t)(k0 + 6) * G4 + col], src[(size_t)(k0 + 7) * G4 + col]);
    whn[i] = o;  // i == ((dir*8+kt)*64+nb)*64+lane
  }
  for (int i = idx; i < 2 * G4; i += stride) {
    int dir = i / G4;
    int j = i % G4;
    const float* src = dir ? b_b : b_f;
    b_p[i] = src[nmap_col(j)];
  }
}

// ---------------- K_emb: gather -> A-fragment layout -----------------------
// m-tile mblk = bg*512 + t holds 16 BATCH rows (bg*16..bg*16+15) at time t.
__global__ void gather_emb(const int* x, const float* embed, uint4* emb_frag) {
  int mblk = blockIdx.x;
  int t = threadIdx.x;
  int bg = mblk >> 9, tloc = mblk & 511;
  __shared__ int xs[16];
  if (t < 16) xs[t] = x[(bg * 16 + t) * TT_LEN + tloc];
  __syncthreads();
  for (int slot = t; slot < 640; slot += 256) {
    int kk = slot >> 6;
    int lane = slot & 63;
    int l15 = lane & 15, quad = lane >> 4;
    int row = xs[l15];
    int kbase = kk * 32 + quad * 8;
    const float* src = embed + (size_t)row * EE;
    float v[8];
#pragma unroll
    for (int e = 0; e < 8; ++e) v[e] = (kbase + e < EE) ? src[kbase + e] : 0.0f;
    uint4 o;
    o.x = packh(v[0], v[1]);
    o.y = packh(v[2], v[3]);
    o.z = packh(v[4], v[5]);
    o.w = packh(v[6], v[7]);
    emb_frag[(size_t)(mblk * 10 + kk) * 64 + lane] = o;
  }
}

// ---------------- K1: xg = emb @ wi^T + b, stored as f16 D-fragments -------
__global__ __launch_bounds__(256) void xg_mfma(
    const uint4* __restrict__ emb_frag, const uint4* __restrict__ wi_frag,
    const float* __restrict__ b_p, uint4* __restrict__ xg_frag) {
  int dir = blockIdx.z;
  int w = threadIdx.x >> 6;
  int lane = threadIdx.x & 63;
  int l15 = lane & 15;
  int mblk = blockIdx.y * 4 + w;

  const uint4* abase = emb_frag + (size_t)mblk * 10 * 64 + lane;
  f32x4 acc[4];
#pragma unroll
  for (int nt = 0; nt < 4; ++nt) acc[nt] = (f32x4){0.f, 0.f, 0.f, 0.f};

#pragma unroll
  for (int kk = 0; kk < 10; ++kk) {
    half8 a = __builtin_bit_cast(half8, abase[kk * 64]);
#pragma unroll
    for (int nt = 0; nt < 4; ++nt) {
      int nb = blockIdx.x * 4 + nt;
      half8 b = __builtin_bit_cast(
          half8, wi_frag[((size_t)(dir * 64 + nb) * 10 + kk) * 64 + lane]);
      acc[nt] = __builtin_amdgcn_mfma_f32_16x16x32_f16(a, b, acc[nt], 0, 0, 0);
    }
  }
#pragma unroll
  for (int ntp = 0; ntp < 2; ++ntp) {
    float bA = b_p[dir * G4 + (blockIdx.x * 4 + 2 * ntp) * 16 + l15];
    float bB = b_p[dir * G4 + (blockIdx.x * 4 + 2 * ntp + 1) * 16 + l15];
    f32x4 aA = acc[2 * ntp], aB = acc[2 * ntp + 1];
    uint4 o;
    o.x = packh(aA[0] + bA, aA[1] + bA);
    o.y = packh(aA[2] + bA, aA[3] + bA);
    o.z = packh(aB[0] + bB, aB[1] + bB);
    o.w = packh(aB[2] + bB, aB[3] + bB);
    xg_frag[((size_t)(dir * 1024 + mblk) * 32 + blockIdx.x * 2 + ntp) * 64 + lane] = o;
  }
}

// ---------------- K2: giant-block MFMA LSTM (no inter-block sync) ----------
// 4 blocks = (dir, bg), 1024 threads = 16 waves. Each block: 16 batch
// recurrences, ALL 1024 gates. Wave w owns nb = w*4+g (unit u = w*16+c).
// Weight tiers (fits the hard 128-reg/wave cap at 16 waves):
//   kt0-4: registers (20 uint4 = 80 VGPR)
//   kt5  : re-streamed from L2 every step (register relief; latency hidden)
//   kt6-7: LDS (128 KB)
// h handoff: hfr = A-FRAGMENT layout double buffer ([2][8kt][64lane] uint4,
// +16B pad/kt-block). Reads are each lane's own contiguous b128 (conflict-
// free); ONE barrier/step (write buf s&1, read buf (s-1)&1).
// ROUND-6 BUG (absmax=1.0): xgp0 base dropped the *64 on the
// (dir*1024+bg*512)*32 term -> 3 of 4 blocks read garbage xg. Fixed below;
// everything else byte-identical to round 6.
__global__ __launch_bounds__(1024) void lstm_mfma(
    const uint4* __restrict__ xg_frag, const uint4* __restrict__ whn,
    unsigned short* __restrict__ h16g) {
  int bid = blockIdx.x;  // dir*2 + bg
  int dir = bid >> 1, bg = bid & 1;
  int t = threadIdx.x;
  int lane = t & 63, w = t >> 6;  // w = 0..15
  int c = lane & 15, q = lane >> 4;

  __shared__ uint4 wlds[8192];              // 128 KB: kt6,7 as [nb*2+kt2][lane]
  __shared__ unsigned short hfr[2 * 4160];  // 16.25 KB A-frag double buffer

  // stage kt6,7 weights
  const uint4* wsrc = whn + (size_t)dir * 32768 + 6 * 4096;
  for (int i = t; i < 8192; i += 1024) {
    int l2 = i & 63, kt2 = (i >> 6) & 1, nb = i >> 7;
    wlds[(nb * 2 + kt2) * 64 + l2] = wsrc[kt2 * 4096 + nb * 64 + l2];
  }
  // zero buf1 (read at s=0; buf0 fully written at s=0 before s=1 reads)
  for (int i = t; i < 2080; i += 1024) ((unsigned int*)hfr)[2080 + i] = 0;

  uint4 wreg[20];
#pragma unroll
  for (int kt = 0; kt < 5; ++kt)
#pragma unroll
    for (int g = 0; g < 4; ++g)
      wreg[kt * 4 + g] =
          whn[(size_t)dir * 32768 + kt * 4096 + (w * 4 + g) * 64 + lane];

  float cst[4] = {0.f, 0.f, 0.f, 0.f};

  const uint4* w5p = whn + (size_t)dir * 32768 + 5 * 4096 + (w * 4) * 64 + lane;
  const uint4* xgp0 =
      xg_frag + ((size_t)(dir * 1024 + bg * 512) * 32 + w * 2) * 64 + lane;
  unsigned short* hgp = h16g + (size_t)dir * 4194304 +
                        (size_t)(w * 16 + c) * 32 + bg * 16 + 4 * q;
  // A-frag write address for h(b=4q+r, u=w*16+c):
  //   kt_w = u>>5 = w>>1; lane' = 4q+r + 16*((u>>3)&3); e = u&7 = c&7
  int aa = (2 * w + (c >> 3)) & 3;
  char* hfrb = (char*)hfr;
  const int wv = (w >> 1) * 1040 + (16 * aa + 4 * q) * 16 + (c & 7) * 2;
  const int rv = lane * 16;

  __syncthreads();

#define MF(A, B, Dd) \
  Dd = __builtin_amdgcn_mfma_f32_16x16x32_f16(A, __builtin_bit_cast(half8, B), Dd, 0, 0, 0)

#define KT_REG(kt, BUFP)                                                     \
  {                                                                          \
    half8 A = *(const half8*)(hfrb + (BUFP)*8320 + (kt)*1040 + rv);          \
    MF(A, wreg[(kt)*4 + 0], D[0]);                                           \
    MF(A, wreg[(kt)*4 + 1], D[1]);                                           \
    MF(A, wreg[(kt)*4 + 2], D[2]);                                           \
    MF(A, wreg[(kt)*4 + 3], D[3]);                                           \
  }

#define KT_W5(BUFP)                                                          \
  {                                                                          \
    half8 A = *(const half8*)(hfrb + (BUFP)*8320 + 5 * 1040 + rv);           \
    MF(A, w5a, D[0]);                                                        \
    MF(A, w5b, D[1]);                                                        \
    MF(A, w5c, D[2]);                                                        \
    MF(A, w5d, D[3]);                                                        \
  }

#define KT_LDS(kt, BUFP)                                                     \
  {                                                                          \
    half8 A = *(const half8*)(hfrb + (BUFP)*8320 + (kt)*1040 + rv);          \
    MF(A, wlds[(w * 8 + 0 * 2 + ((kt)-6)) * 64 + lane], D[0]);               \
    MF(A, wlds[(w * 8 + 1 * 2 + ((kt)-6)) * 64 + lane], D[1]);               \
    MF(A, wlds[(w * 8 + 2 * 2 + ((kt)-6)) * 64 + lane], D[2]);               \
    MF(A, wlds[(w * 8 + 3 * 2 + ((kt)-6)) * 64 + lane], D[3]);               \
  }

#define STEP(SS, BUF)                                                        \
  {                                                                          \
    int tt = dir ? (TT_LEN - 1 - (SS)) : (SS);                               \
    const uint4* xp = xgp0 + (size_t)tt * 2048;                              \
    uint4 w5a = w5p[0];                                                      \
    uint4 w5b = w5p[64];                                                     \
    f32x4 D[4];                                                              \
    D[0] = D[1] = D[2] = D[3] = (f32x4){0.f, 0.f, 0.f, 0.f};                 \
    KT_REG(0, (BUF) ^ 1)                                                     \
    KT_REG(1, (BUF) ^ 1)                                                     \
    KT_REG(2, (BUF) ^ 1)                                                     \
    uint4 w5c = w5p[128];                                                    \
    uint4 w5d = w5p[192];                                                    \
    KT_REG(3, (BUF) ^ 1)                                                     \
    KT_REG(4, (BUF) ^ 1)                                                     \
    uint4 x0 = xp[0];                                                        \
    uint4 x1 = xp[64];                                                       \
    KT_W5((BUF) ^ 1)                                                         \
    KT_LDS(6, (BUF) ^ 1)                                                     \
    KT_LDS(7, (BUF) ^ 1)                                                     \
    float2 p0 = h2f(x0.x), p1 = h2f(x0.y), p2 = h2f(x0.z), p3 = h2f(x0.w);   \
    float2 p4 = h2f(x1.x), p5 = h2f(x1.y), p6 = h2f(x1.z), p7 = h2f(x1.w);   \
    float xi[4] = {p0.x, p0.y, p1.x, p1.y};                                  \
    float xf[4] = {p2.x, p2.y, p3.x, p3.y};                                  \
    float xgv[4] = {p4.x, p4.y, p5.x, p5.y};                                 \
    float xo[4] = {p6.x, p6.y, p7.x, p7.y};                                  \
    float hv[4];                                                             \
    _Pragma("unroll") for (int r = 0; r < 4; ++r) {                          \
      float I = sigm(D[0][r] + xi[r]);                                       \
      float F = sigm(D[1][r] + xf[r]);                                       \
      float G = tanh_f(D[2][r] + xgv[r]);                                    \
      float O = sigm(D[3][r] + xo[r]);                                       \
      float cn = F * cst[r] + I * G;                                         \
      cst[r] = cn;                                                           \
      hv[r] = O * tanh_f(cn);                                                \
      *(unsigned short*)(hfrb + (BUF)*8320 + wv + r * 16) = f16b(hv[r]);     \
    }                                                                        \
    uint2 pk;                                                                \
    pk.x = packh(hv[0], hv[1]);                                              \
    pk.y = packh(hv[2], hv[3]);                                              \
    *(uint2*)(hgp + (size_t)tt * 8192) = pk;                                 \
    __syncthreads();                                                         \
  }

#pragma unroll 1
  for (int s = 0; s < TT_LEN; s += 2) {
    STEP(s, 0)
    STEP(s + 1, 1)
  }
#undef STEP
#undef KT_LDS
#undef KT_W5
#undef KT_REG
#undef MF
}

// ---------------- K3: scores = h . w_out (off the critical path) ----------
__global__ __launch_bounds__(64) void hscore(
    const unsigned short* __restrict__ h16g, const float* __restrict__ w_out,
    float* __restrict__ scores_part) {
  int dt = blockIdx.x;          // 0..1023 = dir*512 + t
  int dir = dt >> 9, tpos = dt & 511;
  int l = threadIdx.x;
  int b = l & 31, uh = l >> 5;
  const unsigned short* base =
      h16g + (((size_t)dir * 512 + tpos) * 256 + uh * 128) * 32 + b;
  const float* wo = w_out + dir * HH + uh * 128;
  float s = 0.f;
#pragma unroll 8
  for (int u = 0; u < 128; ++u) {
    _Float16 hv = __builtin_bit_cast(_Float16, base[(size_t)u * 32]);
    s += (float)hv * wo[u];
  }
  s += __shfl_down(s, 32, 64);
  if (uh == 0) scores_part[((size_t)dir * BB + b) * TT_LEN + tpos] = s;
}

// ---------------- K4: CRF fwd+bwd in PARALLEL WAVES ------------------------
__global__ __launch_bounds__(128) void dp3(const float* __restrict__ scores_part,
                                           const float* __restrict__ b_out,
                                           float* __restrict__ ast_g,
                                           float* __restrict__ bst_g,
                                           float* __restrict__ lzv) {
  int b = blockIdx.x;
  int l = threadIdx.x & 63;
  int w = threadIdx.x >> 6;
  const float* spf = scores_part + (size_t)b * TT_LEN;
  const float* spb = scores_part + (size_t)(BB + b) * TT_LEN;
  float bo = b_out[0];

  float ur[8];
#pragma unroll
  for (int i = 0; i < 8; ++i)
    ur[i] = (spf[i * 64 + l] + spb[i * 64 + l] + bo) * INV_TEMP;

  if (w == 0) {
    float* ast = ast_g + (size_t)b * TT_LEN * AST_STRIDE;
    int lm1 = (l + 63) & 63;
    float a0[3], a1[3];
    float u00 = __shfl(ur[0], 0, 64);
    a0[0] = (l == 1) ? (u00 + TRANS_T) : NEGF;
    a0[1] = NEGF;
    a0[2] = NEGF;
    a1[0] = (l == 0) ? 0.0f : NEGF;
    a1[1] = NEGF;
    a1[2] = NEGF;
    ast[l] = a0[0];
    ast[64 + l] = a0[1];
    if (l < 27) ast[128 + l] = a0[2];

#pragma unroll
    for (int ch = 0; ch < 8; ++ch) {
      float uc = ur[ch];
#pragma unroll 4
      for (int tt = (ch == 0 ? 1 : 0); tt < 64; ++tt) {
        int t = ch * 64 + tt;
        float u0t = __shfl(uc, tt, 64);
        float w0a = __shfl(a0[0], lm1, 64);
        float w1a = __shfl(a0[1], lm1, 64);
        float w2a = __shfl(a0[2], lm1, 64);
        float w0b = __shfl(a1[0], lm1, 64);
        float w1b = __shfl(a1[1], lm1, 64);
        float w2b = __shfl(a1[2], lm1, 64);
        float p0a = (l == 0) ? NEGF : w0a;
        float p1a = (l == 0) ? w0a : w1a;
        float p2a = (l == 0) ? w1a : w2a;
        float p0b = (l == 0) ? NEGF : w0b;
        float p1b = (l == 0) ? w0b : w1b;
        float p2b = (l == 0) ? w1b : w2b;
        float n00 = u0t + la(p0a + TRANS_T, p0b);
        float n01 = u0t + la(p1a + TRANS_T, p1b);
        float n02 = u0t + la(p2a + TRANS_T, p2b);
        float n10 = la(a0[0], a1[0]);
        float n11 = la(a0[1], a1[1]);
        float n12 = la(a0[2], a1[2]);
        a0[0] = n00;
        a0[1] = n01;
        a0[2] = (l < 27) ? n02 : NEGF;
        a1[0] = n10;
        a1[1] = n11;
        a1[2] = (l < 27) ? n12 : NEGF;
        float* astr = ast + (size_t)t * AST_STRIDE;
        astr[l] = a0[0];
        astr[64 + l] = a0[1];
        if (l < 27) astr[128 + l] = a0[2];
      }
    }
    float f00 = a0[0] + TRANS_T, f01 = a0[1] + TRANS_T, f02 = a0[2] + TRANS_T;
    float m = fmaxf(fmaxf(fmaxf(f00, f01), fmaxf(f02, a1[0])),
                    fmaxf(a1[1], a1[2]));
#pragma unroll
    for (int off = 32; off > 0; off >>= 1) m = fmaxf(m, __shfl_xor(m, off, 64));
    float es = __expf(f00 - m) + __expf(f01 - m) + __expf(f02 - m) +
               __expf(a1[0] - m) + __expf(a1[1] - m) + __expf(a1[2] - m);
#pragma unroll
    for (int off = 32; off > 0; off >>= 1) es += __shfl_xor(es, off, 64);
    if (l == 0) lzv[b] = m + __logf(es);
  } else {
    float* bst = bst_g + (size_t)b * TT_LEN * AST_STRIDE;
    int lp1 = (l + 1) & 63;
    float b0[3], b1[3];
    b0[0] = TRANS_T;
    b0[1] = TRANS_T;
    b0[2] = (l < 27) ? TRANS_T : NEGF;
    b1[0] = 0.0f;
    b1[1] = 0.0f;
    b1[2] = (l < 27) ? 0.0f : NEGF;
    {
      float* br = bst + (size_t)(TT_LEN - 1) * AST_STRIDE;
      br[l] = b0[0];
      br[64 + l] = b0[1];
      if (l < 27) br[128 + l] = b0[2];
    }
#pragma unroll
    for (int ch = 7; ch >= 0; --ch) {
      float uc = ur[ch];
#pragma unroll 4
      for (int tt = 63; tt >= (ch == 0 ? 1 : 0); --tt) {
        int t = ch * 64 + tt;
        float u0t = __shfl(uc, tt, 64);
        float w0 = __shfl(b0[0], lp1, 64);
        float w1 = __shfl(b0[1], lp1, 64);
        float w2 = __shfl(b0[2], lp1, 64);
        float x2 = (l == 63) ? NEGF : w2;
        float x1 = (l == 63) ? w2 : w1;
        float x0 = (l == 63) ? w1 : w0;
        float nb00 = la(u0t + TRANS_T + x0, b1[0]);
        float nb01 = la(u0t + TRANS_T + x1, b1[1]);
        float nb02 = la(u0t + TRANS_T + x2, b1[2]);
        float nb10 = la(u0t + x0, b1[0]);
        float nb11 = la(u0t + x1, b1[1]);
        float nb12 = la(u0t + x2, b1[2]);
        b0[0] = nb00;
        b0[1] = nb01;
        b0[2] = (l < 27) ? nb02 : NEGF;
        b1[0] = nb10;
        b1[1] = nb11;
        b1[2] = (l < 27) ? nb12 : NEGF;
        float* br = bst + (size_t)(t - 1) * AST_STRIDE;
        br[l] = b0[0];
        br[64 + l] = b0[1];
        if (l < 27) br[128 + l] = b0[2];
      }
    }
  }
}

// ---------------- K5: marginals, fully parallel ----------------------------
__global__ __launch_bounds__(256) void marg(const float* __restrict__ ast_g,
                                            const float* __restrict__ bst_g,
                                            const float* __restrict__ lzv,
                                            float* __restrict__ out) {
  int row = blockIdx.x * 4 + (threadIdx.x >> 6);
  int l = threadIdx.x & 63;
  int b = row >> 9;
  const float* ar = ast_g + (size_t)row * AST_STRIDE;
  const float* br = bst_g + (size_t)row * AST_STRIDE;
  float lz = lzv[b];
  float s = __expf(ar[l] + br[l] - lz) + __expf(ar[64 + l] + br[64 + l] - lz) +
            ((l < 27) ? __expf(ar[128 + l] + br[128 + l] - lz) : 0.0f);
#pragma unroll
  for (int off = 32; off > 0; off >>= 1) s += __shfl_xor(s, off, 64);
  if (l == 0) out[row] = s;
}

// ---------------------------------------------------------------------------
extern "C" void kernel_launch(void* const* d_in, const int* in_sizes, int n_in,
                              void* d_out, int out_size, void* d_ws, size_t ws_size,
                              hipStream_t stream) {
  const int* x = (const int*)d_in[0];
  const float* embed = (const float*)d_in[3];
  const float* wi_f = (const float*)d_in[4];
  const float* wh_f = (const float*)d_in[5];
  const float* bf = (const float*)d_in[6];
  const float* wi_b = (const float*)d_in[7];
  const float* wh_b = (const float*)d_in[8];
  const float* bbias = (const float*)d_in[9];
  const float* w_out = (const float*)d_in[10];
  const float* b_out = (const float*)d_in[11];

  float* ws = (float*)d_ws;
  float* b_p = ws;                                            // 2048 f32
  unsigned int* wi_frag = (unsigned int*)(b_p + 2 * G4);      // 327680 dw
  uint4* whn = (uint4*)(wi_frag + 2 * 64 * 10 * 64 * 4);      // 65536 uint4
  uint4* emb_frag = whn + 65536;                              // 655360 uint4
  uint4* xg_frag = emb_frag + 655360;                         // 4194304 uint4
  unsigned short* h16g = (unsigned short*)(xg_frag + 4194304);  // 8388608 us
  float* scores_part = (float*)(h16g + 8388608);              // 32768 f32
  float* lzv = scores_part + 2 * BB * TT_LEN;                 // 32 (+pad)
  float* ast_g = lzv + 64;                                    // 32*512*159 f32
  // bst aliases emb_frag (dead after xg_mfma): 10.42 MB fits in 10.49 MB
  float* bst_g = (float*)emb_frag;
  float* outp = (float*)d_out;

  prep_weights<<<256, 256, 0, stream>>>(wi_f, wi_b, wh_f, wh_b, bf, bbias,
                                        wi_frag, b_p, whn);
  gather_emb<<<(BB * TT_LEN) / 16, 256, 0, stream>>>(x, embed, emb_frag);
  dim3 g1(16, 256, 2);
  xg_mfma<<<g1, 256, 0, stream>>>(emb_frag, (const uint4*)wi_frag, b_p, xg_frag);
  lstm_mfma<<<4, 1024, 0, stream>>>(xg_frag, whn, h16g);
  hscore<<<2 * TT_LEN, 64, 0, stream>>>(h16g, w_out, scores_part);
  dp3<<<BB, 128, 0, stream>>>(scores_part, b_out, ast_g, bst_g, lzv);
  marg<<<(BB * TT_LEN) / 4, 256, 0, stream>>>(ast_g, bst_g, lzv, outp);
}